// Round 3
// baseline (694.042 us; speedup 1.0000x reference)
//
#include <hip/hip_runtime.h>
#include <math.h>
#include <stdint.h>

// ---------------- problem constants ----------------
#define BB 2
#define LL 256
#define FLAT 32768
#define DM 1024            // D_MODEL
#define DI 2048            // D_INNER
#define DS 16              // D_STATE
#define DTR 64             // DT_RANK
#define ML (BB*LL)         // 512 rows everywhere

// epilogue selectors
#define EPI_NONE 0
#define EPI_BIAS 1
#define EPI_SOFTPLUS 2
#define EPI_DEC 4          // sigmoid(acc+bias) -> scatter, drop l==255 rows

typedef __attribute__((ext_vector_type(8))) short bf16x8;   // 8 bf16 (4 VGPRs)
typedef __attribute__((ext_vector_type(4))) float f32x4;
typedef __attribute__((ext_vector_type(8))) unsigned short u16x8;
typedef __attribute__((ext_vector_type(4))) unsigned short u16x4;

__device__ __forceinline__ float sigmoid_f(float x) { return 1.0f / (1.0f + __expf(-x)); }

// f32 -> bf16 round-to-nearest-even (inputs finite)
__device__ __forceinline__ unsigned short f2bf(float f) {
    unsigned u = __float_as_uint(f);
    u += 0x7fffu + ((u >> 16) & 1u);
    return (unsigned short)(u >> 16);
}

__device__ __forceinline__ void gld_lds16(const void* g, void* l) {
    __builtin_amdgcn_global_load_lds(
        (const __attribute__((address_space(1))) unsigned int*)g,
        (__attribute__((address_space(3))) unsigned int*)l, 16, 0, 0);
}

// ---------------------------------------------------------------------------
// f32 -> bf16 bulk convert, 8 elems/thread
// ---------------------------------------------------------------------------
__global__ __launch_bounds__(256) void cvt_bf16_k(
    const float* __restrict__ in, unsigned short* __restrict__ out, int n8)
{
    const int i = blockIdx.x * 256 + threadIdx.x;
    if (i >= n8) return;
    const float4 a = ((const float4*)in)[2 * i];
    const float4 b = ((const float4*)in)[2 * i + 1];
    u16x8 r;
    r[0] = f2bf(a.x); r[1] = f2bf(a.y); r[2] = f2bf(a.z); r[3] = f2bf(a.w);
    r[4] = f2bf(b.x); r[5] = f2bf(b.y); r[6] = f2bf(b.z); r[7] = f2bf(b.w);
    ((u16x8*)out)[i] = r;
}

// ---------------------------------------------------------------------------
// bf16 MFMA NT GEMM: C[M,N] = A[M,K] * B[N,K]^T, f32 accumulate.
// 128x128 tile, BK=64, 256 threads (4 waves, 2x2), 64x64 per wave.
// LDS tiles [128 rows][64 bf16] in 16B granules; XOR swizzle (sub ^= row&7)
// applied on the pre-swizzled GLOBAL source and on the READ (rule 21:
// global_load_lds dest stays linear). A and B fragments use the same
// (h,elem)->k map, so the MFMA dot product is correct independent of the
// HW's internal k interleave (sum over k is permutation-invariant).
// ---------------------------------------------------------------------------
template<int EPI, bool SPLIT>
__global__ __launch_bounds__(256) void gemm_bf16(
    const unsigned short* __restrict__ A, const unsigned short* __restrict__ B,
    float* __restrict__ C, int M, int N, int K, int lda, int ldb, int kChunk,
    const float* __restrict__ bias)
{
    __shared__ __align__(16) char lds[32768];   // A: [0,16K)  B: [16K,32K)

    const int t  = threadIdx.x;
    const int w  = t >> 6;          // wave 0..3
    const int l  = t & 63;
    const int m0 = blockIdx.x * 128;
    const int n0 = blockIdx.y * 128;
    const int wr = w >> 1, wc = w & 1;

    int kb = 0, ke = K;
    float* Cout = C;
    if (SPLIT) { kb = blockIdx.z * kChunk; ke = kb + kChunk;
                 Cout = C + (size_t)blockIdx.z * M * N; }

    // staging: granule g = w*256 + q*64 + l ; row = g>>3 ; sub = l&7
    const int srow0 = w * 32 + (l >> 3);
    const int ssub  = l & 7;

    f32x4 acc[4][4];
#pragma unroll
    for (int i = 0; i < 4; ++i)
#pragma unroll
        for (int j = 0; j < 4; ++j) acc[i][j] = (f32x4){0.f, 0.f, 0.f, 0.f};

    const int lr = l & 15, h = l >> 4;

    for (int kt = kb; kt < ke; kt += 64) {
#pragma unroll
        for (int q = 0; q < 4; ++q) {
            const int row = srow0 + q * 8;
            gld_lds16(A + (size_t)(m0 + row) * lda + kt + ((ssub ^ (row & 7)) << 3),
                      lds + w * 4096 + q * 1024);
        }
#pragma unroll
        for (int q = 0; q < 4; ++q) {
            const int row = srow0 + q * 8;
            gld_lds16(B + (size_t)(n0 + row) * ldb + kt + ((ssub ^ (row & 7)) << 3),
                      lds + 16384 + w * 4096 + q * 1024);
        }
        __syncthreads();

#pragma unroll
        for (int ks = 0; ks < 2; ++ks) {
            bf16x8 af[4], bfr[4];
#pragma unroll
            for (int i = 0; i < 4; ++i) {
                const int r = wr * 64 + i * 16 + lr;
                const int sub = (ks * 4 + h) ^ (r & 7);
                af[i] = *(const bf16x8*)(lds + r * 128 + sub * 16);
            }
#pragma unroll
            for (int j = 0; j < 4; ++j) {
                const int c = wc * 64 + j * 16 + lr;
                const int sub = (ks * 4 + h) ^ (c & 7);
                bfr[j] = *(const bf16x8*)(lds + 16384 + c * 128 + sub * 16);
            }
#pragma unroll
            for (int i = 0; i < 4; ++i)
#pragma unroll
                for (int j = 0; j < 4; ++j)
                    acc[i][j] = __builtin_amdgcn_mfma_f32_16x16x32_bf16(
                        af[i], bfr[j], acc[i][j], 0, 0, 0);
        }
        __syncthreads();
    }

    // epilogue — C/D layout (m89-verified): col = lane&15, row = (lane>>4)*4 + reg
#pragma unroll
    for (int i = 0; i < 4; ++i)
#pragma unroll
        for (int j = 0; j < 4; ++j)
#pragma unroll
            for (int rg = 0; rg < 4; ++rg) {
                const int row = m0 + wr * 64 + i * 16 + h * 4 + rg;
                const int col = n0 + wc * 64 + j * 16 + lr;
                float v = acc[i][j][rg];
                if (SPLIT || EPI == EPI_NONE) {
                    Cout[(size_t)row * N + col] = v;
                } else if (EPI == EPI_DEC) {
                    v = sigmoid_f(v + bias[col]);
                    const int b = row >> 8, ll = row & 255;
                    if (ll < 255) Cout[(((size_t)(b * 255 + ll)) << 15) + col] = v;
                }
            }
}

// ---------------------------------------------------------------------------
// f32 NT GEMM (small ops only): 64x64 tile, BK=32
// ---------------------------------------------------------------------------
template<int EPI, bool SPLIT>
__global__ __launch_bounds__(256) void gemm_nt(
    const float* __restrict__ A, const float* __restrict__ B,
    float* __restrict__ C, int M, int N, int K, int lda, int ldb,
    int kChunk, const float* __restrict__ bias)
{
    __shared__ float As[32][64];
    __shared__ float Bs[32][64];

    const int m0 = blockIdx.x * 64;
    const int n0 = blockIdx.y * 64;
    const int t  = threadIdx.x;

    int kb = 0, ke = K;
    float* Cout = C;
    if (SPLIT) { kb = blockIdx.z * kChunk; ke = kb + kChunk; Cout = C + (size_t)blockIdx.z * M * N; }

    const int lrow = t >> 3;
    const int lcol = (t & 7) << 2;

    float acc[4][4];
#pragma unroll
    for (int i = 0; i < 4; ++i)
#pragma unroll
        for (int j = 0; j < 4; ++j) acc[i][j] = 0.0f;

    const int tx = t & 15, ty = t >> 4;

    for (int k = kb; k < ke; k += 32) {
#pragma unroll
        for (int i = 0; i < 2; ++i) {
            const int row = lrow + i * 32;
            float4 av = *(const float4*)&A[(m0 + row) * lda + k + lcol];
            As[lcol + 0][row] = av.x; As[lcol + 1][row] = av.y;
            As[lcol + 2][row] = av.z; As[lcol + 3][row] = av.w;
            const int nn = n0 + row;
            float4 bv = make_float4(0.f, 0.f, 0.f, 0.f);
            if (nn < N) bv = *(const float4*)&B[nn * ldb + k + lcol];
            Bs[lcol + 0][row] = bv.x; Bs[lcol + 1][row] = bv.y;
            Bs[lcol + 2][row] = bv.z; Bs[lcol + 3][row] = bv.w;
        }
        __syncthreads();
#pragma unroll
        for (int kk = 0; kk < 32; ++kk) {
            float4 a4 = *(const float4*)&As[kk][ty << 2];
            float4 b4 = *(const float4*)&Bs[kk][tx << 2];
            const float a[4] = { a4.x, a4.y, a4.z, a4.w };
            const float b[4] = { b4.x, b4.y, b4.z, b4.w };
#pragma unroll
            for (int i = 0; i < 4; ++i)
#pragma unroll
                for (int j = 0; j < 4; ++j)
                    acc[i][j] = fmaf(a[i], b[j], acc[i][j]);
        }
        __syncthreads();
    }

#pragma unroll
    for (int i = 0; i < 4; ++i) {
        const int m = m0 + (ty << 2) + i;
#pragma unroll
        for (int j = 0; j < 4; ++j) {
            const int n = n0 + (tx << 2) + j;
            if (n >= N) continue;
            float v = acc[i][j];
            if (SPLIT || EPI == EPI_NONE) {
                Cout[m * N + n] = v;
            } else if (EPI == EPI_SOFTPLUS) {
                v += bias[n];
                Cout[m * N + n] = fmaxf(v, 0.0f) + log1pf(__expf(-fabsf(v)));
            }
        }
    }
}

// ---------------------------------------------------------------------------
// split-K reduces
// ---------------------------------------------------------------------------
template<int EPI>
__global__ __launch_bounds__(256) void splitk_reduce(
    const float* __restrict__ part, float* __restrict__ C,
    int MN, int N, int S, const float* __restrict__ bias)
{
    const int i = blockIdx.x * 256 + threadIdx.x;
    if (i >= MN) return;
    float s = 0.0f;
    for (int j = 0; j < S; ++j) s += part[(size_t)j * MN + i];
    if (EPI == EPI_BIAS) s += bias[i % N];
    C[i] = s;
}

__global__ __launch_bounds__(256) void splitk_reduce_resid_bf16(
    const float* __restrict__ part, const float* __restrict__ resid,
    unsigned short* __restrict__ outb, int MN, int S)
{
    const int i = blockIdx.x * 256 + threadIdx.x;
    if (i >= MN) return;
    float s = 0.0f;
    for (int j = 0; j < S; ++j) s += part[(size_t)j * MN + i];
    outb[i] = f2bf(s + resid[i]);
}

// ---------------------------------------------------------------------------
// RMSNorm over rows of 1024 -> bf16 output
// ---------------------------------------------------------------------------
__global__ __launch_bounds__(256) void rmsnorm_k(
    const float* __restrict__ x, const float* __restrict__ w,
    unsigned short* __restrict__ o)
{
    const int row = blockIdx.x;
    const int t = threadIdx.x;
    const float* xr = x + row * DM;
    float4 xv = *(const float4*)&xr[t * 4];
    float ss = xv.x * xv.x + xv.y * xv.y + xv.z * xv.z + xv.w * xv.w;
#pragma unroll
    for (int off = 32; off > 0; off >>= 1) ss += __shfl_xor(ss, off);
    __shared__ float red[4];
    if ((t & 63) == 0) red[t >> 6] = ss;
    __syncthreads();
    const float tot = red[0] + red[1] + red[2] + red[3];
    const float scale = rsqrtf(tot * (1.0f / DM) + 1e-5f);
    float4 wv = *(const float4*)&w[t * 4];
    u16x4 ov;
    ov[0] = f2bf(xv.x * scale * wv.x); ov[1] = f2bf(xv.y * scale * wv.y);
    ov[2] = f2bf(xv.z * scale * wv.z); ov[3] = f2bf(xv.w * scale * wv.w);
    *(u16x4*)&o[row * DM + t * 4] = ov;
}

// ---------------------------------------------------------------------------
// causal depthwise conv (width 4) + bias + silu
// ---------------------------------------------------------------------------
__global__ __launch_bounds__(256) void conv_silu_k(
    const float* __restrict__ xz, const float* __restrict__ cw,
    const float* __restrict__ cb, float* __restrict__ u)
{
    const int idx = blockIdx.x * 256 + threadIdx.x;
    if (idx >= ML * DI) return;
    const int d  = idx & (DI - 1);
    const int bl = idx >> 11;
    const int l  = bl & (LL - 1);
    float s = cb[d];
#pragma unroll
    for (int w = 0; w < 4; ++w) {
        const int ls = l - 3 + w;
        if (ls >= 0) s = fmaf(xz[(bl - 3 + w) * (2 * DI) + d], cw[w * DI + d], s);
    }
    u[idx] = s * sigmoid_f(s);
}

// ---------------------------------------------------------------------------
// selective scan + D-skip + silu(z) gating -> bf16 y.
// thread = (b,d,n); 16 lanes per channel, shfl-reduce over states.
// Software-pipelined: iteration l+1's global loads are issued before the
// recurrence math of iteration l (addresses are state-independent), hiding
// HBM/L2 latency under the exp+fma+shfl chain. Only ~4 waves/CU of TLP here,
// so ILP is the latency-hiding mechanism (G7).
// ---------------------------------------------------------------------------
__global__ __launch_bounds__(256) void scan_k(
    const float* __restrict__ dt, const float* __restrict__ u,
    const float* __restrict__ xz, const float* __restrict__ dbc,
    const float* __restrict__ A_log, const float* __restrict__ Dskip,
    unsigned short* __restrict__ y)
{
    const int t = blockIdx.x * 256 + threadIdx.x;
    const int n  = t & (DS - 1);
    const int ch = t >> 4;
    const int d  = ch & (DI - 1);
    const int b  = ch >> 11;
    const float a  = -__expf(A_log[d * DS + n]);
    const float Dv = Dskip[d];
    float h = 0.0f;
    const int rbase = b * LL;

    int r = rbase;
    float dtv = dt[r * DI + d];
    float uv  = u[r * DI + d];
    float Bv  = dbc[r * 96 + DTR + n];
    float Cv  = dbc[r * 96 + DTR + DS + n];
    float zv  = xz[r * (2 * DI) + DI + d];

    for (int l = 0; l < LL; ++l) {
        // prefetch l+1 (wraps to l=0 on last iter — harmless, cached)
        const int rn = rbase + ((l + 1) & (LL - 1));
        const float dtv2 = dt[rn * DI + d];
        const float uv2  = u[rn * DI + d];
        const float Bv2  = dbc[rn * 96 + DTR + n];
        const float Cv2  = dbc[rn * 96 + DTR + DS + n];
        const float zv2  = xz[rn * (2 * DI) + DI + d];

        const float dA = __expf(dtv * a);
        h = fmaf(dA, h, dtv * uv * Bv);
        float p = h * Cv;
        p += __shfl_xor(p, 1); p += __shfl_xor(p, 2);
        p += __shfl_xor(p, 4); p += __shfl_xor(p, 8);
        if (n == 0) {
            const float yy = fmaf(Dv, uv, p);
            y[(rbase + l) * DI + d] = f2bf(yy * zv * sigmoid_f(zv));
        }
        dtv = dtv2; uv = uv2; Bv = Bv2; Cv = Cv2; zv = zv2;
    }
}

// ---------------------------------------------------------------------------
extern "C" void kernel_launch(void* const* d_in, const int* in_sizes, int n_in,
                              void* d_out, int out_size, void* d_ws, size_t ws_size,
                              hipStream_t stream)
{
    const float* x        = (const float*)d_in[0];
    const float* enc_w    = (const float*)d_in[1];
    const float* enc_b    = (const float*)d_in[2];
    const float* dec_w    = (const float*)d_in[3];
    const float* dec_b    = (const float*)d_in[4];
    const float* norm_w   = (const float*)d_in[5];
    const float* in_proj  = (const float*)d_in[6];
    const float* conv_w   = (const float*)d_in[7];
    const float* conv_b   = (const float*)d_in[8];
    const float* x_proj   = (const float*)d_in[9];
    const float* dt_projw = (const float*)d_in[10];
    const float* dt_projb = (const float*)d_in[11];
    const float* A_log    = (const float*)d_in[12];
    const float* D_skip   = (const float*)d_in[13];
    const float* out_proj = (const float*)d_in[14];
    float* out = (float*)d_out;
    (void)in_sizes; (void)n_in; (void)out_size; (void)ws_size;

    // ---- workspace layout (bytes), peak ~130 MiB ----
    // Persistent regions:
    char* wsb = (char*)d_ws;
    unsigned short* wbf = (unsigned short*)(wsb);              // [0, 64Mi)   enc_w, later dec_w
    float* part = (float*)(wsb + 67108864);                    // [64Mi, 96Mi) split-K partials
    float* lat  = (float*)(wsb + 100663296);                   // [96Mi, 98Mi)
    float* dt   = (float*)(wsb + 102760448);                   // [98Mi, 102Mi)
    // Region S (32 MiB): xbf during encoder, then overlaid by post-encoder bufs
    char* S0 = wsb + 106954752;                                // [102Mi, 134Mi)
    unsigned short* xbf    = (unsigned short*)(S0);            // 32 MiB (encoder only)
    unsigned short* inpbf  = (unsigned short*)(S0);            // 8 MiB   (after encoder)
    unsigned short* outpbf = (unsigned short*)(S0 + 8388608);  // 4 MiB
    unsigned short* xnbf   = (unsigned short*)(S0 + 12582912); // 1 MiB
    unsigned short* ybf    = (unsigned short*)(S0 + 13631488); // 2 MiB
    unsigned short* houtbf = (unsigned short*)(S0 + 15728640); // 1 MiB
    float* xz  = (float*)(S0 + 16777216);                      // 8 MiB
    float* u   = (float*)(S0 + 25165824);                      // 4 MiB
    float* dbc = (float*)(S0 + 29360128);                      // 192 KiB

    // 1) convert x and enc_w to bf16 (x is {0,1} -> exact in bf16)
    cvt_bf16_k<<<(FLAT * ML / 8) / 256, 256, 0, stream>>>(x, xbf, FLAT * ML / 8);
    cvt_bf16_k<<<(DM * FLAT / 8) / 256, 256, 0, stream>>>(enc_w, wbf, DM * FLAT / 8);

    // 2) encoder GEMM (split-K 16 -> 512 blocks): lat = x @ enc_w^T + enc_b
    {
        dim3 g(ML / 128, DM / 128, 16);
        gemm_bf16<EPI_NONE, true><<<g, 256, 0, stream>>>(xbf, wbf, part, ML, DM, FLAT,
                                                         FLAT, FLAT, FLAT / 16, nullptr);
        splitk_reduce<EPI_BIAS><<<(ML * DM) / 256, 256, 0, stream>>>(part, lat, ML * DM, DM, 16, enc_b);
    }
    // ---- xbf dead from here; region S reused ----

    // 3) rmsnorm -> bf16
    rmsnorm_k<<<ML, 256, 0, stream>>>(lat, norm_w, xnbf);

    // 4) in_proj: xz = xn @ in_proj^T   (512 x 4096, K=1024)
    cvt_bf16_k<<<(2 * DI * DM / 8) / 256, 256, 0, stream>>>(in_proj, inpbf, 2 * DI * DM / 8);
    {
        dim3 g(ML / 128, (2 * DI) / 128);
        gemm_bf16<EPI_NONE, false><<<g, 256, 0, stream>>>(xnbf, inpbf, xz, ML, 2 * DI, DM,
                                                          DM, DM, 0, nullptr);
    }

    // 5) conv + silu -> u (f32)
    conv_silu_k<<<(ML * DI) / 256, 256, 0, stream>>>(xz, conv_w, conv_b, u);

    // 6) x_proj (f32, split-K 16): dbc = u @ x_proj^T  (512 x 96, K=2048)
    {
        dim3 g(ML / 64, 2, 16);
        gemm_nt<EPI_NONE, true><<<g, 256, 0, stream>>>(u, x_proj, part, ML, 96, DI, DI, DI,
                                                       DI / 16, nullptr);
        splitk_reduce<EPI_NONE><<<(ML * 96 + 255) / 256, 256, 0, stream>>>(part, dbc, ML * 96, 96, 16, nullptr);
    }

    // 7) dt = softplus(dbc[:, :64] @ dt_proj_w^T + dt_proj_b)  (512 x 2048, K=64)
    {
        dim3 g(ML / 64, DI / 64);
        gemm_nt<EPI_SOFTPLUS, false><<<g, 256, 0, stream>>>(dbc, dt_projw, dt, ML, DI, DTR,
                                                            96, DTR, 0, dt_projb);
    }

    // 8) selective scan + gating -> ybf
    scan_k<<<(BB * DI * DS) / 256, 256, 0, stream>>>(dt, u, xz, dbc, A_log, D_skip, ybf);

    // 9) out_proj (split-K 8) + residual(lat) -> houtbf
    cvt_bf16_k<<<(DM * DI / 8) / 256, 256, 0, stream>>>(out_proj, outpbf, DM * DI / 8);
    {
        dim3 g(ML / 128, DM / 128, 8);
        gemm_bf16<EPI_NONE, true><<<g, 256, 0, stream>>>(ybf, outpbf, part, ML, DM, DI,
                                                         DI, DI, DI / 8, nullptr);
        splitk_reduce_resid_bf16<<<(ML * DM) / 256, 256, 0, stream>>>(part, lat, houtbf, ML * DM, 8);
    }

    // 10) decoder: out = sigmoid(hout @ dec_w^T + dec_b), drop l==255 rows
    cvt_bf16_k<<<(FLAT * DM / 8) / 256, 256, 0, stream>>>(dec_w, wbf, FLAT * DM / 8);
    {
        dim3 g(ML / 128, FLAT / 128);
        gemm_bf16<EPI_DEC, false><<<g, 256, 0, stream>>>(houtbf, wbf, out, ML, FLAT, DM,
                                                         DM, DM, 0, dec_b);
    }
}

// Round 4
// 645.889 us; speedup vs baseline: 1.0746x; 1.0746x over previous
//
#include <hip/hip_runtime.h>
#include <math.h>
#include <stdint.h>

// ---------------- problem constants ----------------
#define BB 2
#define LL 256
#define FLAT 32768
#define DM 1024            // D_MODEL
#define DI 2048            // D_INNER
#define DS 16              // D_STATE
#define DTR 64             // DT_RANK
#define ML (BB*LL)         // 512 rows everywhere

// epilogue selectors
#define EPI_NONE 0
#define EPI_BIAS 1
#define EPI_SOFTPLUS 2
#define EPI_DEC 4          // sigmoid(acc+bias) -> scatter, drop l==255 rows

typedef __attribute__((ext_vector_type(8))) short bf16x8;   // 8 bf16 (4 VGPRs)
typedef __attribute__((ext_vector_type(4))) float f32x4;
typedef __attribute__((ext_vector_type(8))) unsigned short u16x8;
typedef __attribute__((ext_vector_type(4))) unsigned short u16x4;

__device__ __forceinline__ float sigmoid_f(float x) { return 1.0f / (1.0f + __expf(-x)); }

// f32 -> bf16 round-to-nearest-even (inputs finite)
__device__ __forceinline__ unsigned short f2bf(float f) {
    unsigned u = __float_as_uint(f);
    u += 0x7fffu + ((u >> 16) & 1u);
    return (unsigned short)(u >> 16);
}

__device__ __forceinline__ void gld_lds16(const void* g, void* l) {
    __builtin_amdgcn_global_load_lds(
        (const __attribute__((address_space(1))) unsigned int*)g,
        (__attribute__((address_space(3))) unsigned int*)l, 16, 0, 0);
}

// ---------------------------------------------------------------------------
// f32 -> bf16 bulk convert, 8 elems/thread
// ---------------------------------------------------------------------------
__global__ __launch_bounds__(256) void cvt_bf16_k(
    const float* __restrict__ in, unsigned short* __restrict__ out, int n8)
{
    const int i = blockIdx.x * 256 + threadIdx.x;
    if (i >= n8) return;
    const float4 a = ((const float4*)in)[2 * i];
    const float4 b = ((const float4*)in)[2 * i + 1];
    u16x8 r;
    r[0] = f2bf(a.x); r[1] = f2bf(a.y); r[2] = f2bf(a.z); r[3] = f2bf(a.w);
    r[4] = f2bf(b.x); r[5] = f2bf(b.y); r[6] = f2bf(b.z); r[7] = f2bf(b.w);
    ((u16x8*)out)[i] = r;
}

// ---------------------------------------------------------------------------
// bf16 MFMA NT GEMM: C[M,N] = A[M,K] * B[N,K]^T, f32 accumulate.
// 128x128 tile, BK=64, 256 threads (4 waves, 2x2), 64x64 per wave.
// LDS tiles [128 rows][64 bf16] in 16B granules; XOR swizzle (sub ^= row&7)
// applied on the pre-swizzled GLOBAL source and on the READ (rule 21:
// global_load_lds dest stays linear). A and B fragments use the same
// (h,elem)->k map, so the MFMA dot product is correct independent of the
// HW's internal k interleave (sum over k is permutation-invariant).
// ---------------------------------------------------------------------------
template<int EPI, bool SPLIT>
__global__ __launch_bounds__(256) void gemm_bf16(
    const unsigned short* __restrict__ A, const unsigned short* __restrict__ B,
    float* __restrict__ C, int M, int N, int K, int lda, int ldb, int kChunk,
    const float* __restrict__ bias)
{
    __shared__ __align__(16) char lds[32768];   // A: [0,16K)  B: [16K,32K)

    const int t  = threadIdx.x;
    const int w  = t >> 6;          // wave 0..3
    const int l  = t & 63;
    const int m0 = blockIdx.x * 128;
    const int n0 = blockIdx.y * 128;
    const int wr = w >> 1, wc = w & 1;

    int kb = 0, ke = K;
    float* Cout = C;
    if (SPLIT) { kb = blockIdx.z * kChunk; ke = kb + kChunk;
                 Cout = C + (size_t)blockIdx.z * M * N; }

    // staging: granule g = w*256 + q*64 + l ; row = g>>3 ; sub = l&7
    const int srow0 = w * 32 + (l >> 3);
    const int ssub  = l & 7;

    f32x4 acc[4][4];
#pragma unroll
    for (int i = 0; i < 4; ++i)
#pragma unroll
        for (int j = 0; j < 4; ++j) acc[i][j] = (f32x4){0.f, 0.f, 0.f, 0.f};

    const int lr = l & 15, h = l >> 4;

    for (int kt = kb; kt < ke; kt += 64) {
#pragma unroll
        for (int q = 0; q < 4; ++q) {
            const int row = srow0 + q * 8;
            gld_lds16(A + (size_t)(m0 + row) * lda + kt + ((ssub ^ (row & 7)) << 3),
                      lds + w * 4096 + q * 1024);
        }
#pragma unroll
        for (int q = 0; q < 4; ++q) {
            const int row = srow0 + q * 8;
            gld_lds16(B + (size_t)(n0 + row) * ldb + kt + ((ssub ^ (row & 7)) << 3),
                      lds + 16384 + w * 4096 + q * 1024);
        }
        __syncthreads();

#pragma unroll
        for (int ks = 0; ks < 2; ++ks) {
            bf16x8 af[4], bfr[4];
#pragma unroll
            for (int i = 0; i < 4; ++i) {
                const int r = wr * 64 + i * 16 + lr;
                const int sub = (ks * 4 + h) ^ (r & 7);
                af[i] = *(const bf16x8*)(lds + r * 128 + sub * 16);
            }
#pragma unroll
            for (int j = 0; j < 4; ++j) {
                const int c = wc * 64 + j * 16 + lr;
                const int sub = (ks * 4 + h) ^ (c & 7);
                bfr[j] = *(const bf16x8*)(lds + 16384 + c * 128 + sub * 16);
            }
#pragma unroll
            for (int i = 0; i < 4; ++i)
#pragma unroll
                for (int j = 0; j < 4; ++j)
                    acc[i][j] = __builtin_amdgcn_mfma_f32_16x16x32_bf16(
                        af[i], bfr[j], acc[i][j], 0, 0, 0);
        }
        __syncthreads();
    }

    // epilogue — C/D layout (m89-verified): col = lane&15, row = (lane>>4)*4 + reg
#pragma unroll
    for (int i = 0; i < 4; ++i)
#pragma unroll
        for (int j = 0; j < 4; ++j)
#pragma unroll
            for (int rg = 0; rg < 4; ++rg) {
                const int row = m0 + wr * 64 + i * 16 + h * 4 + rg;
                const int col = n0 + wc * 64 + j * 16 + lr;
                float v = acc[i][j][rg];
                if (SPLIT || EPI == EPI_NONE) {
                    Cout[(size_t)row * N + col] = v;
                } else if (EPI == EPI_DEC) {
                    v = sigmoid_f(v + bias[col]);
                    const int b = row >> 8, ll = row & 255;
                    if (ll < 255) Cout[(((size_t)(b * 255 + ll)) << 15) + col] = v;
                }
            }
}

// ---------------------------------------------------------------------------
// f32 NT GEMM (small ops only): 64x64 tile, BK=32
// ---------------------------------------------------------------------------
template<int EPI, bool SPLIT>
__global__ __launch_bounds__(256) void gemm_nt(
    const float* __restrict__ A, const float* __restrict__ B,
    float* __restrict__ C, int M, int N, int K, int lda, int ldb,
    int kChunk, const float* __restrict__ bias)
{
    __shared__ float As[32][64];
    __shared__ float Bs[32][64];

    const int m0 = blockIdx.x * 64;
    const int n0 = blockIdx.y * 64;
    const int t  = threadIdx.x;

    int kb = 0, ke = K;
    float* Cout = C;
    if (SPLIT) { kb = blockIdx.z * kChunk; ke = kb + kChunk; Cout = C + (size_t)blockIdx.z * M * N; }

    const int lrow = t >> 3;
    const int lcol = (t & 7) << 2;

    float acc[4][4];
#pragma unroll
    for (int i = 0; i < 4; ++i)
#pragma unroll
        for (int j = 0; j < 4; ++j) acc[i][j] = 0.0f;

    const int tx = t & 15, ty = t >> 4;

    for (int k = kb; k < ke; k += 32) {
#pragma unroll
        for (int i = 0; i < 2; ++i) {
            const int row = lrow + i * 32;
            float4 av = *(const float4*)&A[(m0 + row) * lda + k + lcol];
            As[lcol + 0][row] = av.x; As[lcol + 1][row] = av.y;
            As[lcol + 2][row] = av.z; As[lcol + 3][row] = av.w;
            const int nn = n0 + row;
            float4 bv = make_float4(0.f, 0.f, 0.f, 0.f);
            if (nn < N) bv = *(const float4*)&B[nn * ldb + k + lcol];
            Bs[lcol + 0][row] = bv.x; Bs[lcol + 1][row] = bv.y;
            Bs[lcol + 2][row] = bv.z; Bs[lcol + 3][row] = bv.w;
        }
        __syncthreads();
#pragma unroll
        for (int kk = 0; kk < 32; ++kk) {
            float4 a4 = *(const float4*)&As[kk][ty << 2];
            float4 b4 = *(const float4*)&Bs[kk][tx << 2];
            const float a[4] = { a4.x, a4.y, a4.z, a4.w };
            const float b[4] = { b4.x, b4.y, b4.z, b4.w };
#pragma unroll
            for (int i = 0; i < 4; ++i)
#pragma unroll
                for (int j = 0; j < 4; ++j)
                    acc[i][j] = fmaf(a[i], b[j], acc[i][j]);
        }
        __syncthreads();
    }

#pragma unroll
    for (int i = 0; i < 4; ++i) {
        const int m = m0 + (ty << 2) + i;
#pragma unroll
        for (int j = 0; j < 4; ++j) {
            const int n = n0 + (tx << 2) + j;
            if (n >= N) continue;
            float v = acc[i][j];
            if (SPLIT || EPI == EPI_NONE) {
                Cout[m * N + n] = v;
            } else if (EPI == EPI_SOFTPLUS) {
                v += bias[n];
                Cout[m * N + n] = fmaxf(v, 0.0f) + log1pf(__expf(-fabsf(v)));
            }
        }
    }
}

// ---------------------------------------------------------------------------
// split-K reduces
// ---------------------------------------------------------------------------
template<int EPI>
__global__ __launch_bounds__(256) void splitk_reduce(
    const float* __restrict__ part, float* __restrict__ C,
    int MN, int N, int S, const float* __restrict__ bias)
{
    const int i = blockIdx.x * 256 + threadIdx.x;
    if (i >= MN) return;
    float s = 0.0f;
    for (int j = 0; j < S; ++j) s += part[(size_t)j * MN + i];
    if (EPI == EPI_BIAS) s += bias[i % N];
    C[i] = s;
}

__global__ __launch_bounds__(256) void splitk_reduce_resid_bf16(
    const float* __restrict__ part, const float* __restrict__ resid,
    unsigned short* __restrict__ outb, int MN, int S)
{
    const int i = blockIdx.x * 256 + threadIdx.x;
    if (i >= MN) return;
    float s = 0.0f;
    for (int j = 0; j < S; ++j) s += part[(size_t)j * MN + i];
    outb[i] = f2bf(s + resid[i]);
}

// ---------------------------------------------------------------------------
// RMSNorm over rows of 1024 -> bf16 output
// ---------------------------------------------------------------------------
__global__ __launch_bounds__(256) void rmsnorm_k(
    const float* __restrict__ x, const float* __restrict__ w,
    unsigned short* __restrict__ o)
{
    const int row = blockIdx.x;
    const int t = threadIdx.x;
    const float* xr = x + row * DM;
    float4 xv = *(const float4*)&xr[t * 4];
    float ss = xv.x * xv.x + xv.y * xv.y + xv.z * xv.z + xv.w * xv.w;
#pragma unroll
    for (int off = 32; off > 0; off >>= 1) ss += __shfl_xor(ss, off);
    __shared__ float red[4];
    if ((t & 63) == 0) red[t >> 6] = ss;
    __syncthreads();
    const float tot = red[0] + red[1] + red[2] + red[3];
    const float scale = rsqrtf(tot * (1.0f / DM) + 1e-5f);
    float4 wv = *(const float4*)&w[t * 4];
    u16x4 ov;
    ov[0] = f2bf(xv.x * scale * wv.x); ov[1] = f2bf(xv.y * scale * wv.y);
    ov[2] = f2bf(xv.z * scale * wv.z); ov[3] = f2bf(xv.w * scale * wv.w);
    *(u16x4*)&o[row * DM + t * 4] = ov;
}

// ---------------------------------------------------------------------------
// causal depthwise conv (width 4) + bias + silu
// ---------------------------------------------------------------------------
__global__ __launch_bounds__(256) void conv_silu_k(
    const float* __restrict__ xz, const float* __restrict__ cw,
    const float* __restrict__ cb, float* __restrict__ u)
{
    const int idx = blockIdx.x * 256 + threadIdx.x;
    if (idx >= ML * DI) return;
    const int d  = idx & (DI - 1);
    const int bl = idx >> 11;
    const int l  = bl & (LL - 1);
    float s = cb[d];
#pragma unroll
    for (int w = 0; w < 4; ++w) {
        const int ls = l - 3 + w;
        if (ls >= 0) s = fmaf(xz[(bl - 3 + w) * (2 * DI) + d], cw[w * DI + d], s);
    }
    u[idx] = s * sigmoid_f(s);
}

// ---------------------------------------------------------------------------
// selective scan + D-skip + silu(z) gating -> bf16 y.
// thread = (b,d,n); 16 lanes per channel.
// Latency fix (r3 profile: 108us, VALUBusy 22%, Occ 11% = 1 wave/SIMD,
// latency-bound): process L in chunks of 8. Per chunk: (1) issue all 40
// loads up front (one vmem drain per 8 steps instead of ~5 waits/step);
// (2) run the 8-step recurrence as a pure-VALU chain, banking p[s]=h*C;
// (3) run the 8 shuffle-reduce trees AFTER, level-by-level across s, so
// the ~35cy DS latency pipelines 8-wide instead of serializing. The only
// true loop-carried dep is h=fma(dA,h,dtBu) (~20cy/step).
// ---------------------------------------------------------------------------
__global__ __launch_bounds__(256) void scan_k(
    const float* __restrict__ dt, const float* __restrict__ u,
    const float* __restrict__ xz, const float* __restrict__ dbc,
    const float* __restrict__ A_log, const float* __restrict__ Dskip,
    unsigned short* __restrict__ y)
{
    const int t = blockIdx.x * 256 + threadIdx.x;
    const int n  = t & (DS - 1);
    const int ch = t >> 4;
    const int d  = ch & (DI - 1);
    const int b  = ch >> 11;
    const float a  = -__expf(A_log[d * DS + n]);
    const float Dv = Dskip[d];
    float h = 0.0f;
    const int rbase = b * LL;

    for (int l0 = 0; l0 < LL; l0 += 8) {
        float dtv[8], uv[8], Bv[8], Cv[8], zv[8];
#pragma unroll
        for (int s = 0; s < 8; ++s) {
            const int r = rbase + l0 + s;
            dtv[s] = dt[r * DI + d];
            uv[s]  = u[r * DI + d];
            Bv[s]  = dbc[r * 96 + DTR + n];
            Cv[s]  = dbc[r * 96 + DTR + DS + n];
            zv[s]  = xz[r * (2 * DI) + DI + d];
        }
        float p[8];
#pragma unroll
        for (int s = 0; s < 8; ++s) {
            const float dA = __expf(dtv[s] * a);
            h = fmaf(dA, h, dtv[s] * uv[s] * Bv[s]);
            p[s] = h * Cv[s];
        }
        // deferred reduction: 8 independent 4-level trees, level-major for ILP
#pragma unroll
        for (int s = 0; s < 8; ++s) p[s] += __shfl_xor(p[s], 1);
#pragma unroll
        for (int s = 0; s < 8; ++s) p[s] += __shfl_xor(p[s], 2);
#pragma unroll
        for (int s = 0; s < 8; ++s) p[s] += __shfl_xor(p[s], 4);
#pragma unroll
        for (int s = 0; s < 8; ++s) p[s] += __shfl_xor(p[s], 8);
        if (n == 0) {
#pragma unroll
            for (int s = 0; s < 8; ++s) {
                const int r = rbase + l0 + s;
                const float yy = fmaf(Dv, uv[s], p[s]);
                y[r * DI + d] = f2bf(yy * zv[s] * sigmoid_f(zv[s]));
            }
        }
    }
}

// ---------------------------------------------------------------------------
extern "C" void kernel_launch(void* const* d_in, const int* in_sizes, int n_in,
                              void* d_out, int out_size, void* d_ws, size_t ws_size,
                              hipStream_t stream)
{
    const float* x        = (const float*)d_in[0];
    const float* enc_w    = (const float*)d_in[1];
    const float* enc_b    = (const float*)d_in[2];
    const float* dec_w    = (const float*)d_in[3];
    const float* dec_b    = (const float*)d_in[4];
    const float* norm_w   = (const float*)d_in[5];
    const float* in_proj  = (const float*)d_in[6];
    const float* conv_w   = (const float*)d_in[7];
    const float* conv_b   = (const float*)d_in[8];
    const float* x_proj   = (const float*)d_in[9];
    const float* dt_projw = (const float*)d_in[10];
    const float* dt_projb = (const float*)d_in[11];
    const float* A_log    = (const float*)d_in[12];
    const float* D_skip   = (const float*)d_in[13];
    const float* out_proj = (const float*)d_in[14];
    float* out = (float*)d_out;
    (void)in_sizes; (void)n_in; (void)out_size; (void)ws_size;

    // ---- workspace layout (bytes), peak ~130 MiB ----
    char* wsb = (char*)d_ws;
    unsigned short* wbf = (unsigned short*)(wsb);              // [0, 64Mi)   enc_w, later dec_w
    float* part = (float*)(wsb + 67108864);                    // [64Mi, 96Mi) split-K partials
    float* lat  = (float*)(wsb + 100663296);                   // [96Mi, 98Mi)
    float* dt   = (float*)(wsb + 102760448);                   // [98Mi, 102Mi)
    // Region S (32 MiB): xbf during encoder, then overlaid by post-encoder bufs
    char* S0 = wsb + 106954752;                                // [102Mi, 134Mi)
    unsigned short* xbf    = (unsigned short*)(S0);            // 32 MiB (encoder only)
    unsigned short* inpbf  = (unsigned short*)(S0);            // 8 MiB   (after encoder)
    unsigned short* outpbf = (unsigned short*)(S0 + 8388608);  // 4 MiB
    unsigned short* xnbf   = (unsigned short*)(S0 + 12582912); // 1 MiB
    unsigned short* ybf    = (unsigned short*)(S0 + 13631488); // 2 MiB
    unsigned short* houtbf = (unsigned short*)(S0 + 15728640); // 1 MiB
    float* xz  = (float*)(S0 + 16777216);                      // 8 MiB
    float* u   = (float*)(S0 + 25165824);                      // 4 MiB
    float* dbc = (float*)(S0 + 29360128);                      // 192 KiB

    // 1) convert x and enc_w to bf16 (x is {0,1} -> exact in bf16)
    cvt_bf16_k<<<(FLAT * ML / 8) / 256, 256, 0, stream>>>(x, xbf, FLAT * ML / 8);
    cvt_bf16_k<<<(DM * FLAT / 8) / 256, 256, 0, stream>>>(enc_w, wbf, DM * FLAT / 8);

    // 2) encoder GEMM (split-K 16 -> 512 blocks): lat = x @ enc_w^T + enc_b
    {
        dim3 g(ML / 128, DM / 128, 16);
        gemm_bf16<EPI_NONE, true><<<g, 256, 0, stream>>>(xbf, wbf, part, ML, DM, FLAT,
                                                         FLAT, FLAT, FLAT / 16, nullptr);
        splitk_reduce<EPI_BIAS><<<(ML * DM) / 256, 256, 0, stream>>>(part, lat, ML * DM, DM, 16, enc_b);
    }
    // ---- xbf dead from here; region S reused ----

    // 3) rmsnorm -> bf16
    rmsnorm_k<<<ML, 256, 0, stream>>>(lat, norm_w, xnbf);

    // 4) in_proj: xz = xn @ in_proj^T   (512 x 4096, K=1024)
    cvt_bf16_k<<<(2 * DI * DM / 8) / 256, 256, 0, stream>>>(in_proj, inpbf, 2 * DI * DM / 8);
    {
        dim3 g(ML / 128, (2 * DI) / 128);
        gemm_bf16<EPI_NONE, false><<<g, 256, 0, stream>>>(xnbf, inpbf, xz, ML, 2 * DI, DM,
                                                          DM, DM, 0, nullptr);
    }

    // 5) conv + silu -> u (f32)
    conv_silu_k<<<(ML * DI) / 256, 256, 0, stream>>>(xz, conv_w, conv_b, u);

    // 6) x_proj (f32, split-K 16): dbc = u @ x_proj^T  (512 x 96, K=2048)
    {
        dim3 g(ML / 64, 2, 16);
        gemm_nt<EPI_NONE, true><<<g, 256, 0, stream>>>(u, x_proj, part, ML, 96, DI, DI, DI,
                                                       DI / 16, nullptr);
        splitk_reduce<EPI_NONE><<<(ML * 96 + 255) / 256, 256, 0, stream>>>(part, dbc, ML * 96, 96, 16, nullptr);
    }

    // 7) dt = softplus(dbc[:, :64] @ dt_proj_w^T + dt_proj_b)  (512 x 2048, K=64)
    {
        dim3 g(ML / 64, DI / 64);
        gemm_nt<EPI_SOFTPLUS, false><<<g, 256, 0, stream>>>(dbc, dt_projw, dt, ML, DI, DTR,
                                                            96, DTR, 0, dt_projb);
    }

    // 8) selective scan + gating -> ybf
    scan_k<<<(BB * DI * DS) / 256, 256, 0, stream>>>(dt, u, xz, dbc, A_log, D_skip, ybf);

    // 9) out_proj (split-K 8) + residual(lat) -> houtbf
    cvt_bf16_k<<<(DM * DI / 8) / 256, 256, 0, stream>>>(out_proj, outpbf, DM * DI / 8);
    {
        dim3 g(ML / 128, DM / 128, 8);
        gemm_bf16<EPI_NONE, true><<<g, 256, 0, stream>>>(ybf, outpbf, part, ML, DM, DI,
                                                         DI, DI, DI / 8, nullptr);
        splitk_reduce_resid_bf16<<<(ML * DM) / 256, 256, 0, stream>>>(part, lat, houtbf, ML * DM, 8);
    }

    // 10) decoder: out = sigmoid(hout @ dec_w^T + dec_b), drop l==255 rows
    cvt_bf16_k<<<(FLAT * DM / 8) / 256, 256, 0, stream>>>(dec_w, wbf, FLAT * DM / 8);
    {
        dim3 g(ML / 128, FLAT / 128);
        gemm_bf16<EPI_DEC, false><<<g, 256, 0, stream>>>(houtbf, wbf, out, ML, FLAT, DM,
                                                         DM, DM, 0, dec_b);
    }
}

// Round 7
// 634.570 us; speedup vs baseline: 1.0937x; 1.0178x over previous
//
#include <hip/hip_runtime.h>
#include <math.h>
#include <stdint.h>

// ---------------- problem constants ----------------
#define BB 2
#define LL 256
#define FLAT 32768
#define DM 1024            // D_MODEL
#define DI 2048            // D_INNER
#define DS 16              // D_STATE
#define DTR 64             // DT_RANK
#define ML (BB*LL)         // 512 rows everywhere

// epilogue selectors
#define EPI_NONE 0
#define EPI_BIAS 1
#define EPI_SOFTPLUS 2
#define EPI_DEC 4          // sigmoid(acc+bias) -> scatter, drop l==255 rows

typedef __attribute__((ext_vector_type(8))) short bf16x8;   // 8 bf16 (4 VGPRs)
typedef __attribute__((ext_vector_type(4))) float f32x4;
typedef __attribute__((ext_vector_type(8))) unsigned short u16x8;
typedef __attribute__((ext_vector_type(4))) unsigned short u16x4;

__device__ __forceinline__ float sigmoid_f(float x) { return 1.0f / (1.0f + __expf(-x)); }

// f32 -> bf16 round-to-nearest-even (inputs finite)
__device__ __forceinline__ unsigned short f2bf(float f) {
    unsigned u = __float_as_uint(f);
    u += 0x7fffu + ((u >> 16) & 1u);
    return (unsigned short)(u >> 16);
}

// packed f32x2 -> bf16x2 (RNE, hardware) — no builtin on gfx950, inline asm
__device__ __forceinline__ unsigned cvt_pk_bf16(float a, float b) {
    unsigned r;
    asm("v_cvt_pk_bf16_f32 %0, %1, %2" : "=v"(r) : "v"(a), "v"(b));
    return r;
}

__device__ __forceinline__ void gld_lds16(const void* g, void* l) {
    __builtin_amdgcn_global_load_lds(
        (const __attribute__((address_space(1))) unsigned int*)g,
        (__attribute__((address_space(3))) unsigned int*)l, 16, 0, 0);
}

// ---------------------------------------------------------------------------
// f32 -> bf16 bulk convert, 8 elems/thread (only used for x now)
// ---------------------------------------------------------------------------
__global__ __launch_bounds__(256) void cvt_bf16_k(
    const float* __restrict__ in, unsigned short* __restrict__ out, int n8)
{
    const int i = blockIdx.x * 256 + threadIdx.x;
    if (i >= n8) return;
    const float4 a = ((const float4*)in)[2 * i];
    const float4 b = ((const float4*)in)[2 * i + 1];
    u16x8 r;
    r[0] = f2bf(a.x); r[1] = f2bf(a.y); r[2] = f2bf(a.z); r[3] = f2bf(a.w);
    r[4] = f2bf(b.x); r[5] = f2bf(b.y); r[6] = f2bf(b.z); r[7] = f2bf(b.w);
    ((u16x8*)out)[i] = r;
}

// ---------------------------------------------------------------------------
// bf16 MFMA NT GEMM: C[M,N] = A[M,K] * B[N,K]^T, f32 accumulate.
// 128x128 tile, BK=64, 256 threads (4 waves, 2x2), 64x64 per wave.
// A: bf16 in memory, staged via global_load_lds (16B granules, 8/row,
//    XOR row&7 pre-swizzled source, swizzled read).
// B (BF32=true): *f32* in memory — fused convert-on-read. Staged raw f32
//    via global_load_lds (16B granules, 16/row, XOR row&15 pre-swizzled
//    source); fragment read = 2x ds_read_b128 + 4x v_cvt_pk_bf16_f32.
//    Byte-level k-map identical to the bf16 path, so the A/B fragment
//    k-order invariance is preserved. Read aliasing 2-way = free.
// B (BF32=false): bf16 like A.
// ---------------------------------------------------------------------------
template<int EPI, bool SPLIT, bool BF32>
__global__ __launch_bounds__(256) void gemm_bf16(
    const unsigned short* __restrict__ A, const void* __restrict__ Bv,
    float* __restrict__ C, int M, int N, int K, int lda, int ldb, int kChunk,
    const float* __restrict__ bias)
{
    __shared__ __align__(16) char lds[BF32 ? 49152 : 32768]; // A:[0,16K) B:[16K,...)

    const float*          Bf = (const float*)Bv;
    const unsigned short* Bh = (const unsigned short*)Bv;

    const int t  = threadIdx.x;
    const int w  = t >> 6;          // wave 0..3
    const int l  = t & 63;
    const int m0 = blockIdx.x * 128;
    const int n0 = blockIdx.y * 128;
    const int wr = w >> 1, wc = w & 1;

    int kb = 0, ke = K;
    float* Cout = C;
    if (SPLIT) { kb = blockIdx.z * kChunk; ke = kb + kChunk;
                 Cout = C + (size_t)blockIdx.z * M * N; }

    // A staging: granule g = w*256 + q*64 + l ; row = g>>3 ; sub = l&7
    const int srow0 = w * 32 + (l >> 3);
    const int ssub  = l & 7;
    // B f32 staging: granule g = w*512 + q*64 + l ; row = g>>4 ; gl = l&15
    const int brow0 = w * 32 + (l >> 4);
    const int bgl   = l & 15;

    f32x4 acc[4][4];
#pragma unroll
    for (int i = 0; i < 4; ++i)
#pragma unroll
        for (int j = 0; j < 4; ++j) acc[i][j] = (f32x4){0.f, 0.f, 0.f, 0.f};

    const int lr = l & 15, h = l >> 4;

    for (int kt = kb; kt < ke; kt += 64) {
#pragma unroll
        for (int q = 0; q < 4; ++q) {
            const int row = srow0 + q * 8;
            gld_lds16(A + (size_t)(m0 + row) * lda + kt + ((ssub ^ (row & 7)) << 3),
                      lds + w * 4096 + q * 1024);
        }
        if (BF32) {
#pragma unroll
            for (int q = 0; q < 8; ++q) {
                const int row = brow0 + q * 4;
                gld_lds16(Bf + (size_t)(n0 + row) * ldb + kt + ((bgl ^ (row & 15)) << 2),
                          lds + 16384 + w * 8192 + q * 1024);
            }
        } else {
#pragma unroll
            for (int q = 0; q < 4; ++q) {
                const int row = srow0 + q * 8;
                gld_lds16(Bh + (size_t)(n0 + row) * ldb + kt + ((ssub ^ (row & 7)) << 3),
                          lds + 16384 + w * 4096 + q * 1024);
            }
        }
        __syncthreads();

#pragma unroll
        for (int ks = 0; ks < 2; ++ks) {
            bf16x8 af[4], bfr[4];
#pragma unroll
            for (int i = 0; i < 4; ++i) {
                const int r = wr * 64 + i * 16 + lr;
                const int sub = (ks * 4 + h) ^ (r & 7);
                af[i] = *(const bf16x8*)(lds + r * 128 + sub * 16);
            }
#pragma unroll
            for (int j = 0; j < 4; ++j) {
                const int c = wc * 64 + j * 16 + lr;
                if (BF32) {
                    const int g0 = (2 * (ks * 4 + h))     ^ (c & 15);
                    const int g1 = (2 * (ks * 4 + h) + 1) ^ (c & 15);
                    const f32x4 v0 = *(const f32x4*)(lds + 16384 + c * 256 + g0 * 16);
                    const f32x4 v1 = *(const f32x4*)(lds + 16384 + c * 256 + g1 * 16);
                    union { unsigned u[4]; bf16x8 v; } cv;
                    cv.u[0] = cvt_pk_bf16(v0[0], v0[1]);
                    cv.u[1] = cvt_pk_bf16(v0[2], v0[3]);
                    cv.u[2] = cvt_pk_bf16(v1[0], v1[1]);
                    cv.u[3] = cvt_pk_bf16(v1[2], v1[3]);
                    bfr[j] = cv.v;
                } else {
                    const int sub = (ks * 4 + h) ^ (c & 7);
                    bfr[j] = *(const bf16x8*)(lds + 16384 + c * 128 + sub * 16);
                }
            }
#pragma unroll
            for (int i = 0; i < 4; ++i)
#pragma unroll
                for (int j = 0; j < 4; ++j)
                    acc[i][j] = __builtin_amdgcn_mfma_f32_16x16x32_bf16(
                        af[i], bfr[j], acc[i][j], 0, 0, 0);
        }
        __syncthreads();
    }

    // epilogue — C/D layout (m89-verified): col = lane&15, row = (lane>>4)*4 + reg
#pragma unroll
    for (int i = 0; i < 4; ++i)
#pragma unroll
        for (int j = 0; j < 4; ++j)
#pragma unroll
            for (int rg = 0; rg < 4; ++rg) {
                const int row = m0 + wr * 64 + i * 16 + h * 4 + rg;
                const int col = n0 + wc * 64 + j * 16 + lr;
                float v = acc[i][j][rg];
                if (SPLIT || EPI == EPI_NONE) {
                    Cout[(size_t)row * N + col] = v;
                } else if (EPI == EPI_DEC) {
                    v = sigmoid_f(v + bias[col]);
                    const int b = row >> 8, ll = row & 255;
                    if (ll < 255) Cout[(((size_t)(b * 255 + ll)) << 15) + col] = v;
                }
            }
}

// ---------------------------------------------------------------------------
// f32 NT GEMM (small ops only): 64x64 tile, BK=32
// ---------------------------------------------------------------------------
template<int EPI, bool SPLIT>
__global__ __launch_bounds__(256) void gemm_nt(
    const float* __restrict__ A, const float* __restrict__ B,
    float* __restrict__ C, int M, int N, int K, int lda, int ldb,
    int kChunk, const float* __restrict__ bias)
{
    __shared__ float As[32][64];
    __shared__ float Bs[32][64];

    const int m0 = blockIdx.x * 64;
    const int n0 = blockIdx.y * 64;
    const int t  = threadIdx.x;

    int kb = 0, ke = K;
    float* Cout = C;
    if (SPLIT) { kb = blockIdx.z * kChunk; ke = kb + kChunk; Cout = C + (size_t)blockIdx.z * M * N; }

    const int lrow = t >> 3;
    const int lcol = (t & 7) << 2;

    float acc[4][4];
#pragma unroll
    for (int i = 0; i < 4; ++i)
#pragma unroll
        for (int j = 0; j < 4; ++j) acc[i][j] = 0.0f;

    const int tx = t & 15, ty = t >> 4;

    for (int k = kb; k < ke; k += 32) {
#pragma unroll
        for (int i = 0; i < 2; ++i) {
            const int row = lrow + i * 32;
            float4 av = *(const float4*)&A[(m0 + row) * lda + k + lcol];
            As[lcol + 0][row] = av.x; As[lcol + 1][row] = av.y;
            As[lcol + 2][row] = av.z; As[lcol + 3][row] = av.w;
            const int nn = n0 + row;
            float4 bv = make_float4(0.f, 0.f, 0.f, 0.f);
            if (nn < N) bv = *(const float4*)&B[nn * ldb + k + lcol];
            Bs[lcol + 0][row] = bv.x; Bs[lcol + 1][row] = bv.y;
            Bs[lcol + 2][row] = bv.z; Bs[lcol + 3][row] = bv.w;
        }
        __syncthreads();
#pragma unroll
        for (int kk = 0; kk < 32; ++kk) {
            float4 a4 = *(const float4*)&As[kk][ty << 2];
            float4 b4 = *(const float4*)&Bs[kk][tx << 2];
            const float a[4] = { a4.x, a4.y, a4.z, a4.w };
            const float b[4] = { b4.x, b4.y, b4.z, b4.w };
#pragma unroll
            for (int i = 0; i < 4; ++i)
#pragma unroll
                for (int j = 0; j < 4; ++j)
                    acc[i][j] = fmaf(a[i], b[j], acc[i][j]);
        }
        __syncthreads();
    }

#pragma unroll
    for (int i = 0; i < 4; ++i) {
        const int m = m0 + (ty << 2) + i;
#pragma unroll
        for (int j = 0; j < 4; ++j) {
            const int n = n0 + (tx << 2) + j;
            if (n >= N) continue;
            float v = acc[i][j];
            if (SPLIT || EPI == EPI_NONE) {
                Cout[m * N + n] = v;
            } else if (EPI == EPI_SOFTPLUS) {
                v += bias[n];
                Cout[m * N + n] = fmaxf(v, 0.0f) + log1pf(__expf(-fabsf(v)));
            }
        }
    }
}

// ---------------------------------------------------------------------------
// split-K reduces
// ---------------------------------------------------------------------------
template<int EPI>
__global__ __launch_bounds__(256) void splitk_reduce(
    const float* __restrict__ part, float* __restrict__ C,
    int MN, int N, int S, const float* __restrict__ bias)
{
    const int i = blockIdx.x * 256 + threadIdx.x;
    if (i >= MN) return;
    float s = 0.0f;
    for (int j = 0; j < S; ++j) s += part[(size_t)j * MN + i];
    if (EPI == EPI_BIAS) s += bias[i % N];
    C[i] = s;
}

__global__ __launch_bounds__(256) void splitk_reduce_resid_bf16(
    const float* __restrict__ part, const float* __restrict__ resid,
    unsigned short* __restrict__ outb, int MN, int S)
{
    const int i = blockIdx.x * 256 + threadIdx.x;
    if (i >= MN) return;
    float s = 0.0f;
    for (int j = 0; j < S; ++j) s += part[(size_t)j * MN + i];
    outb[i] = f2bf(s + resid[i]);
}

// ---------------------------------------------------------------------------
// RMSNorm over rows of 1024 -> bf16 output
// ---------------------------------------------------------------------------
__global__ __launch_bounds__(256) void rmsnorm_k(
    const float* __restrict__ x, const float* __restrict__ w,
    unsigned short* __restrict__ o)
{
    const int row = blockIdx.x;
    const int t = threadIdx.x;
    const float* xr = x + row * DM;
    float4 xv = *(const float4*)&xr[t * 4];
    float ss = xv.x * xv.x + xv.y * xv.y + xv.z * xv.z + xv.w * xv.w;
#pragma unroll
    for (int off = 32; off > 0; off >>= 1) ss += __shfl_xor(ss, off);
    __shared__ float red[4];
    if ((t & 63) == 0) red[t >> 6] = ss;
    __syncthreads();
    const float tot = red[0] + red[1] + red[2] + red[3];
    const float scale = rsqrtf(tot * (1.0f / DM) + 1e-5f);
    float4 wv = *(const float4*)&w[t * 4];
    u16x4 ov;
    ov[0] = f2bf(xv.x * scale * wv.x); ov[1] = f2bf(xv.y * scale * wv.y);
    ov[2] = f2bf(xv.z * scale * wv.z); ov[3] = f2bf(xv.w * scale * wv.w);
    *(u16x4*)&o[row * DM + t * 4] = ov;
}

// ---------------------------------------------------------------------------
// causal depthwise conv (width 4) + bias + silu
// ---------------------------------------------------------------------------
__global__ __launch_bounds__(256) void conv_silu_k(
    const float* __restrict__ xz, const float* __restrict__ cw,
    const float* __restrict__ cb, float* __restrict__ u)
{
    const int idx = blockIdx.x * 256 + threadIdx.x;
    if (idx >= ML * DI) return;
    const int d  = idx & (DI - 1);
    const int bl = idx >> 11;
    const int l  = bl & (LL - 1);
    float s = cb[d];
#pragma unroll
    for (int w = 0; w < 4; ++w) {
        const int ls = l - 3 + w;
        if (ls >= 0) s = fmaf(xz[(bl - 3 + w) * (2 * DI) + d], cw[w * DI + d], s);
    }
    u[idx] = s * sigmoid_f(s);
}

// ---------------------------------------------------------------------------
// selective scan + D-skip + silu(z) gating -> bf16 y.  (r4: 8-step chunked,
// batched loads + deferred level-major shuffle reduction — fixed the 108us
// latency-bound profile; no longer in top-5.)
// ---------------------------------------------------------------------------
__global__ __launch_bounds__(256) void scan_k(
    const float* __restrict__ dt, const float* __restrict__ u,
    const float* __restrict__ xz, const float* __restrict__ dbc,
    const float* __restrict__ A_log, const float* __restrict__ Dskip,
    unsigned short* __restrict__ y)
{
    const int t = blockIdx.x * 256 + threadIdx.x;
    const int n  = t & (DS - 1);
    const int ch = t >> 4;
    const int d  = ch & (DI - 1);
    const int b  = ch >> 11;
    const float a  = -__expf(A_log[d * DS + n]);
    const float Dv = Dskip[d];
    float h = 0.0f;
    const int rbase = b * LL;

    for (int l0 = 0; l0 < LL; l0 += 8) {
        float dtv[8], uv[8], Bv[8], Cv[8], zv[8];
#pragma unroll
        for (int s = 0; s < 8; ++s) {
            const int r = rbase + l0 + s;
            dtv[s] = dt[r * DI + d];
            uv[s]  = u[r * DI + d];
            Bv[s]  = dbc[r * 96 + DTR + n];
            Cv[s]  = dbc[r * 96 + DTR + DS + n];
            zv[s]  = xz[r * (2 * DI) + DI + d];
        }
        float p[8];
#pragma unroll
        for (int s = 0; s < 8; ++s) {
            const float dA = __expf(dtv[s] * a);
            h = fmaf(dA, h, dtv[s] * uv[s] * Bv[s]);
            p[s] = h * Cv[s];
        }
#pragma unroll
        for (int s = 0; s < 8; ++s) p[s] += __shfl_xor(p[s], 1);
#pragma unroll
        for (int s = 0; s < 8; ++s) p[s] += __shfl_xor(p[s], 2);
#pragma unroll
        for (int s = 0; s < 8; ++s) p[s] += __shfl_xor(p[s], 4);
#pragma unroll
        for (int s = 0; s < 8; ++s) p[s] += __shfl_xor(p[s], 8);
        if (n == 0) {
#pragma unroll
            for (int s = 0; s < 8; ++s) {
                const int r = rbase + l0 + s;
                const float yy = fmaf(Dv, uv[s], p[s]);
                y[r * DI + d] = f2bf(yy * zv[s] * sigmoid_f(zv[s]));
            }
        }
    }
}

// ---------------------------------------------------------------------------
extern "C" void kernel_launch(void* const* d_in, const int* in_sizes, int n_in,
                              void* d_out, int out_size, void* d_ws, size_t ws_size,
                              hipStream_t stream)
{
    const float* x        = (const float*)d_in[0];
    const float* enc_w    = (const float*)d_in[1];
    const float* enc_b    = (const float*)d_in[2];
    const float* dec_w    = (const float*)d_in[3];
    const float* dec_b    = (const float*)d_in[4];
    const float* norm_w   = (const float*)d_in[5];
    const float* in_proj  = (const float*)d_in[6];
    const float* conv_w   = (const float*)d_in[7];
    const float* conv_b   = (const float*)d_in[8];
    const float* x_proj   = (const float*)d_in[9];
    const float* dt_projw = (const float*)d_in[10];
    const float* dt_projb = (const float*)d_in[11];
    const float* A_log    = (const float*)d_in[12];
    const float* D_skip   = (const float*)d_in[13];
    const float* out_proj = (const float*)d_in[14];
    float* out = (float*)d_out;
    (void)in_sizes; (void)n_in; (void)out_size; (void)ws_size;

    // ---- workspace layout (bytes), peak ~102 MiB ----
    char* wsb = (char*)d_ws;
    float* part = (float*)(wsb);                               // [0, 64Mi)  split-K partials (32 slices)
    float* lat  = (float*)(wsb + 67108864);                    // 2 MiB
    float* dt   = (float*)(wsb + 69206016);                    // 4 MiB
    // Region S (32 MiB): xbf during encoder, then overlaid
    char* S0 = wsb + 73400320;
    unsigned short* xbf    = (unsigned short*)(S0);            // 32 MiB (encoder only)
    unsigned short* xnbf   = (unsigned short*)(S0);            // 1 MiB  (after encoder)
    unsigned short* ybf    = (unsigned short*)(S0 + 1048576);  // 2 MiB
    unsigned short* houtbf = (unsigned short*)(S0 + 3145728);  // 1 MiB
    float* xz  = (float*)(S0 + 4194304);                       // 8 MiB
    float* u   = (float*)(S0 + 12582912);                      // 4 MiB
    float* dbc = (float*)(S0 + 16777216);                      // 192 KiB

    // 1) convert x to bf16 ({0,1} -> exact). Weights are NOT pre-converted:
    //    conversion is fused into GEMM B-staging (saves ~384 MiB HBM/call).
    cvt_bf16_k<<<(FLAT * ML / 8) / 256, 256, 0, stream>>>(x, xbf, FLAT * ML / 8);

    // 2) encoder GEMM (split-K 32 -> 1024 blocks, 4/CU): lat = x @ enc_w^T + enc_b
    {
        dim3 g(ML / 128, DM / 128, 32);
        gemm_bf16<EPI_NONE, true, true><<<g, 256, 0, stream>>>(
            xbf, enc_w, part, ML, DM, FLAT, FLAT, FLAT, FLAT / 32, nullptr);
        splitk_reduce<EPI_BIAS><<<(ML * DM) / 256, 256, 0, stream>>>(part, lat, ML * DM, DM, 32, enc_b);
    }
    // ---- xbf dead from here; region S reused ----

    // 3) rmsnorm -> bf16
    rmsnorm_k<<<ML, 256, 0, stream>>>(lat, norm_w, xnbf);

    // 4) in_proj: xz = xn @ in_proj^T   (512 x 4096, K=1024), fused f32 B
    {
        dim3 g(ML / 128, (2 * DI) / 128);
        gemm_bf16<EPI_NONE, false, true><<<g, 256, 0, stream>>>(
            xnbf, in_proj, xz, ML, 2 * DI, DM, DM, DM, 0, nullptr);
    }

    // 5) conv + silu -> u (f32)
    conv_silu_k<<<(ML * DI) / 256, 256, 0, stream>>>(xz, conv_w, conv_b, u);

    // 6) x_proj (f32, split-K 16): dbc = u @ x_proj^T  (512 x 96, K=2048)
    {
        dim3 g(ML / 64, 2, 16);
        gemm_nt<EPI_NONE, true><<<g, 256, 0, stream>>>(u, x_proj, part, ML, 96, DI, DI, DI,
                                                       DI / 16, nullptr);
        splitk_reduce<EPI_NONE><<<(ML * 96 + 255) / 256, 256, 0, stream>>>(part, dbc, ML * 96, 96, 16, nullptr);
    }

    // 7) dt = softplus(dbc[:, :64] @ dt_proj_w^T + dt_proj_b)  (512 x 2048, K=64)
    {
        dim3 g(ML / 64, DI / 64);
        gemm_nt<EPI_SOFTPLUS, false><<<g, 256, 0, stream>>>(dbc, dt_projw, dt, ML, DI, DTR,
                                                            96, DTR, 0, dt_projb);
    }

    // 8) selective scan + gating -> ybf
    scan_k<<<(BB * DI * DS) / 256, 256, 0, stream>>>(dt, u, xz, dbc, A_log, D_skip, ybf);

    // 9) out_proj (split-K 8, fused f32 B) + residual(lat) -> houtbf
    {
        dim3 g(ML / 128, DM / 128, 8);
        gemm_bf16<EPI_NONE, true, true><<<g, 256, 0, stream>>>(
            ybf, out_proj, part, ML, DM, DI, DI, DI, DI / 8, nullptr);
        splitk_reduce_resid_bf16<<<(ML * DM) / 256, 256, 0, stream>>>(part, lat, houtbf, ML * DM, 8);
    }

    // 10) decoder (fused f32 B): out = sigmoid(hout @ dec_w^T + dec_b), drop l==255
    {
        dim3 g(ML / 128, FLAT / 128);
        gemm_bf16<EPI_DEC, false, true><<<g, 256, 0, stream>>>(
            houtbf, dec_w, out, ML, FLAT, DM, DM, DM, 0, dec_b);
    }
}

// Round 9
// 633.477 us; speedup vs baseline: 1.0956x; 1.0017x over previous
//
#include <hip/hip_runtime.h>
#include <math.h>
#include <stdint.h>

// ---------------- problem constants ----------------
#define BB 2
#define LL 256
#define FLAT 32768
#define DM 1024            // D_MODEL
#define DI 2048            // D_INNER
#define DS 16              // D_STATE
#define DTR 64             // DT_RANK
#define ML (BB*LL)         // 512 rows everywhere

// epilogue selectors
#define EPI_NONE 0
#define EPI_BIAS 1
#define EPI_SOFTPLUS 2
#define EPI_DEC 4          // sigmoid(acc+bias) -> scatter, drop l==255 rows

typedef __attribute__((ext_vector_type(8))) short bf16x8;   // 8 bf16 (4 VGPRs)
typedef __attribute__((ext_vector_type(4))) float f32x4;
typedef __attribute__((ext_vector_type(8))) unsigned short u16x8;
typedef __attribute__((ext_vector_type(4))) unsigned short u16x4;

__device__ __forceinline__ float sigmoid_f(float x) { return 1.0f / (1.0f + __expf(-x)); }

// f32 -> bf16 round-to-nearest-even (inputs finite)
__device__ __forceinline__ unsigned short f2bf(float f) {
    unsigned u = __float_as_uint(f);
    u += 0x7fffu + ((u >> 16) & 1u);
    return (unsigned short)(u >> 16);
}

// packed f32x2 -> bf16x2 (RNE, hardware) — no builtin on gfx950, inline asm
__device__ __forceinline__ unsigned cvt_pk_bf16(float a, float b) {
    unsigned r;
    asm("v_cvt_pk_bf16_f32 %0, %1, %2" : "=v"(r) : "v"(a), "v"(b));
    return r;
}

__device__ __forceinline__ void gld_lds16(const void* g, void* l) {
    __builtin_amdgcn_global_load_lds(
        (const __attribute__((address_space(1))) unsigned int*)g,
        (__attribute__((address_space(3))) unsigned int*)l, 16, 0, 0);
}

// ---------------------------------------------------------------------------
// f32 -> bf16 bulk convert, 8 elems/thread (x, enc_w, dec_w)
// ---------------------------------------------------------------------------
__global__ __launch_bounds__(256) void cvt_bf16_k(
    const float* __restrict__ in, unsigned short* __restrict__ out, int n8)
{
    const int i = blockIdx.x * 256 + threadIdx.x;
    if (i >= n8) return;
    const float4 a = ((const float4*)in)[2 * i];
    const float4 b = ((const float4*)in)[2 * i + 1];
    u16x8 r;
    r[0] = f2bf(a.x); r[1] = f2bf(a.y); r[2] = f2bf(a.z); r[3] = f2bf(a.w);
    r[4] = f2bf(b.x); r[5] = f2bf(b.y); r[6] = f2bf(b.z); r[7] = f2bf(b.w);
    ((u16x8*)out)[i] = r;
}

// ---------------------------------------------------------------------------
// 2-phase double-buffered bf16 MFMA NT GEMM (T3 minimum recipe, m248):
// per tile t: STAGE(buf[cur^1], t+1) FIRST, then ds_read+MFMA from buf[cur],
// then own-wave vmcnt(0) + raw s_barrier. HBM loads stay in flight under the
// compute phase instead of draining at a pre-compute __syncthreads (the r7
// profile's duty-cycle stall: 3.2TB/s, MfmaUtil 11%).
// 128x128 tile, BK=64, 256 thr (4 waves 2x2), LDS 2x32K.
// XOR swizzle (sub ^= row&7) on pre-swizzled GLOBAL source + swizzled READ;
// linear gld_lds dest (rule 21). A/B share the (h,elem)->k map.
// ---------------------------------------------------------------------------
template<int EPI, bool SPLIT>
__global__ __launch_bounds__(256) void gemm_db(
    const unsigned short* __restrict__ A, const unsigned short* __restrict__ B,
    float* __restrict__ C, int M, int N, int K, int lda, int ldb, int kChunk,
    const float* __restrict__ bias)
{
    __shared__ __align__(16) char lds[65536];   // buf p: A at p*32768, B at +16384

    const int t  = threadIdx.x;
    const int w  = t >> 6;
    const int l  = t & 63;
    const int m0 = blockIdx.x * 128;
    const int n0 = blockIdx.y * 128;
    const int wr = w >> 1, wc = w & 1;

    int kb = 0, ke = K;
    float* Cout = C;
    if (SPLIT) { kb = blockIdx.z * kChunk; ke = kb + kChunk;
                 Cout = C + (size_t)blockIdx.z * M * N; }

    const int srow0 = w * 32 + (l >> 3);
    const int ssub  = l & 7;

    f32x4 acc[4][4];
#pragma unroll
    for (int i = 0; i < 4; ++i)
#pragma unroll
        for (int j = 0; j < 4; ++j) acc[i][j] = (f32x4){0.f, 0.f, 0.f, 0.f};

    const int lr = l & 15, h = l >> 4;

    // stage tile (k-offset kt) into buffer p
    auto STAGE = [&](int p, int kt) {
#pragma unroll
        for (int q = 0; q < 4; ++q) {
            const int row = srow0 + q * 8;
            gld_lds16(A + (size_t)(m0 + row) * lda + kt + ((ssub ^ (row & 7)) << 3),
                      lds + p * 32768 + w * 4096 + q * 1024);
        }
#pragma unroll
        for (int q = 0; q < 4; ++q) {
            const int row = srow0 + q * 8;
            gld_lds16(B + (size_t)(n0 + row) * ldb + kt + ((ssub ^ (row & 7)) << 3),
                      lds + p * 32768 + 16384 + w * 4096 + q * 1024);
        }
    };

    STAGE(0, kb);
    asm volatile("s_waitcnt vmcnt(0)" ::: "memory");
    __builtin_amdgcn_s_barrier();

    const int nt = (ke - kb) >> 6;
    int cur = 0;
    for (int tt = 0; tt < nt; ++tt) {
        if (tt + 1 < nt) STAGE(cur ^ 1, kb + ((tt + 1) << 6));   // loads in flight
        const char* la = lds + cur * 32768;
        const char* lb = la + 16384;
#pragma unroll
        for (int ks = 0; ks < 2; ++ks) {
            bf16x8 af[4], bfr[4];
#pragma unroll
            for (int i = 0; i < 4; ++i) {
                const int r = wr * 64 + i * 16 + lr;
                const int sub = (ks * 4 + h) ^ (r & 7);
                af[i] = *(const bf16x8*)(la + r * 128 + sub * 16);
            }
#pragma unroll
            for (int j = 0; j < 4; ++j) {
                const int c = wc * 64 + j * 16 + lr;
                const int sub = (ks * 4 + h) ^ (c & 7);
                bfr[j] = *(const bf16x8*)(lb + c * 128 + sub * 16);
            }
#pragma unroll
            for (int i = 0; i < 4; ++i)
#pragma unroll
                for (int j = 0; j < 4; ++j)
                    acc[i][j] = __builtin_amdgcn_mfma_f32_16x16x32_bf16(
                        af[i], bfr[j], acc[i][j], 0, 0, 0);
        }
        // next tile's loads complete under the compute above; sync buffers
        asm volatile("s_waitcnt vmcnt(0)" ::: "memory");
        __builtin_amdgcn_s_barrier();
        cur ^= 1;
    }

    // epilogue — C/D layout (m89-verified): col = lane&15, row = (lane>>4)*4 + reg
#pragma unroll
    for (int i = 0; i < 4; ++i)
#pragma unroll
        for (int j = 0; j < 4; ++j)
#pragma unroll
            for (int rg = 0; rg < 4; ++rg) {
                const int row = m0 + wr * 64 + i * 16 + h * 4 + rg;
                const int col = n0 + wc * 64 + j * 16 + lr;
                float v = acc[i][j][rg];
                if (SPLIT || EPI == EPI_NONE) {
                    Cout[(size_t)row * N + col] = v;
                } else if (EPI == EPI_DEC) {
                    v = sigmoid_f(v + bias[col]);
                    const int b = row >> 8, ll = row & 255;
                    if (ll < 255) Cout[(((size_t)(b * 255 + ll)) << 15) + col] = v;
                }
            }
}

// ---------------------------------------------------------------------------
// single-buffer MFMA NT GEMM with fused f32-B convert (kept from r7 for the
// small cache-resident weights: in_proj 16MiB, out_proj 8MiB)
// ---------------------------------------------------------------------------
template<int EPI, bool SPLIT, bool BF32>
__global__ __launch_bounds__(256) void gemm_bf16(
    const unsigned short* __restrict__ A, const void* __restrict__ Bv,
    float* __restrict__ C, int M, int N, int K, int lda, int ldb, int kChunk,
    const float* __restrict__ bias)
{
    __shared__ __align__(16) char lds[BF32 ? 49152 : 32768];

    const float*          Bf = (const float*)Bv;
    const unsigned short* Bh = (const unsigned short*)Bv;

    const int t  = threadIdx.x;
    const int w  = t >> 6;
    const int l  = t & 63;
    const int m0 = blockIdx.x * 128;
    const int n0 = blockIdx.y * 128;
    const int wr = w >> 1, wc = w & 1;

    int kb = 0, ke = K;
    float* Cout = C;
    if (SPLIT) { kb = blockIdx.z * kChunk; ke = kb + kChunk;
                 Cout = C + (size_t)blockIdx.z * M * N; }

    const int srow0 = w * 32 + (l >> 3);
    const int ssub  = l & 7;
    const int brow0 = w * 32 + (l >> 4);
    const int bgl   = l & 15;

    f32x4 acc[4][4];
#pragma unroll
    for (int i = 0; i < 4; ++i)
#pragma unroll
        for (int j = 0; j < 4; ++j) acc[i][j] = (f32x4){0.f, 0.f, 0.f, 0.f};

    const int lr = l & 15, h = l >> 4;

    for (int kt = kb; kt < ke; kt += 64) {
#pragma unroll
        for (int q = 0; q < 4; ++q) {
            const int row = srow0 + q * 8;
            gld_lds16(A + (size_t)(m0 + row) * lda + kt + ((ssub ^ (row & 7)) << 3),
                      lds + w * 4096 + q * 1024);
        }
        if (BF32) {
#pragma unroll
            for (int q = 0; q < 8; ++q) {
                const int row = brow0 + q * 4;
                gld_lds16(Bf + (size_t)(n0 + row) * ldb + kt + ((bgl ^ (row & 15)) << 2),
                          lds + 16384 + w * 8192 + q * 1024);
            }
        } else {
#pragma unroll
            for (int q = 0; q < 4; ++q) {
                const int row = srow0 + q * 8;
                gld_lds16(Bh + (size_t)(n0 + row) * ldb + kt + ((ssub ^ (row & 7)) << 3),
                          lds + 16384 + w * 4096 + q * 1024);
            }
        }
        __syncthreads();

#pragma unroll
        for (int ks = 0; ks < 2; ++ks) {
            bf16x8 af[4], bfr[4];
#pragma unroll
            for (int i = 0; i < 4; ++i) {
                const int r = wr * 64 + i * 16 + lr;
                const int sub = (ks * 4 + h) ^ (r & 7);
                af[i] = *(const bf16x8*)(lds + r * 128 + sub * 16);
            }
#pragma unroll
            for (int j = 0; j < 4; ++j) {
                const int c = wc * 64 + j * 16 + lr;
                if (BF32) {
                    const int g0 = (2 * (ks * 4 + h))     ^ (c & 15);
                    const int g1 = (2 * (ks * 4 + h) + 1) ^ (c & 15);
                    const f32x4 v0 = *(const f32x4*)(lds + 16384 + c * 256 + g0 * 16);
                    const f32x4 v1 = *(const f32x4*)(lds + 16384 + c * 256 + g1 * 16);
                    union { unsigned u[4]; bf16x8 v; } cv;
                    cv.u[0] = cvt_pk_bf16(v0[0], v0[1]);
                    cv.u[1] = cvt_pk_bf16(v0[2], v0[3]);
                    cv.u[2] = cvt_pk_bf16(v1[0], v1[1]);
                    cv.u[3] = cvt_pk_bf16(v1[2], v1[3]);
                    bfr[j] = cv.v;
                } else {
                    const int sub = (ks * 4 + h) ^ (c & 7);
                    bfr[j] = *(const bf16x8*)(lds + 16384 + c * 128 + sub * 16);
                }
            }
#pragma unroll
            for (int i = 0; i < 4; ++i)
#pragma unroll
                for (int j = 0; j < 4; ++j)
                    acc[i][j] = __builtin_amdgcn_mfma_f32_16x16x32_bf16(
                        af[i], bfr[j], acc[i][j], 0, 0, 0);
        }
        __syncthreads();
    }

#pragma unroll
    for (int i = 0; i < 4; ++i)
#pragma unroll
        for (int j = 0; j < 4; ++j)
#pragma unroll
            for (int rg = 0; rg < 4; ++rg) {
                const int row = m0 + wr * 64 + i * 16 + h * 4 + rg;
                const int col = n0 + wc * 64 + j * 16 + lr;
                float v = acc[i][j][rg];
                if (SPLIT || EPI == EPI_NONE) {
                    Cout[(size_t)row * N + col] = v;
                } else if (EPI == EPI_DEC) {
                    v = sigmoid_f(v + bias[col]);
                    const int b = row >> 8, ll = row & 255;
                    if (ll < 255) Cout[(((size_t)(b * 255 + ll)) << 15) + col] = v;
                }
            }
}

// ---------------------------------------------------------------------------
// f32 NT GEMM (small ops only): 64x64 tile, BK=32
// ---------------------------------------------------------------------------
template<int EPI, bool SPLIT>
__global__ __launch_bounds__(256) void gemm_nt(
    const float* __restrict__ A, const float* __restrict__ B,
    float* __restrict__ C, int M, int N, int K, int lda, int ldb,
    int kChunk, const float* __restrict__ bias)
{
    __shared__ float As[32][64];
    __shared__ float Bs[32][64];

    const int m0 = blockIdx.x * 64;
    const int n0 = blockIdx.y * 64;
    const int t  = threadIdx.x;

    int kb = 0, ke = K;
    float* Cout = C;
    if (SPLIT) { kb = blockIdx.z * kChunk; ke = kb + kChunk; Cout = C + (size_t)blockIdx.z * M * N; }

    const int lrow = t >> 3;
    const int lcol = (t & 7) << 2;

    float acc[4][4];
#pragma unroll
    for (int i = 0; i < 4; ++i)
#pragma unroll
        for (int j = 0; j < 4; ++j) acc[i][j] = 0.0f;

    const int tx = t & 15, ty = t >> 4;

    for (int k = kb; k < ke; k += 32) {
#pragma unroll
        for (int i = 0; i < 2; ++i) {
            const int row = lrow + i * 32;
            float4 av = *(const float4*)&A[(m0 + row) * lda + k + lcol];
            As[lcol + 0][row] = av.x; As[lcol + 1][row] = av.y;
            As[lcol + 2][row] = av.z; As[lcol + 3][row] = av.w;
            const int nn = n0 + row;
            float4 bv = make_float4(0.f, 0.f, 0.f, 0.f);
            if (nn < N) bv = *(const float4*)&B[nn * ldb + k + lcol];
            Bs[lcol + 0][row] = bv.x; Bs[lcol + 1][row] = bv.y;
            Bs[lcol + 2][row] = bv.z; Bs[lcol + 3][row] = bv.w;
        }
        __syncthreads();
#pragma unroll
        for (int kk = 0; kk < 32; ++kk) {
            float4 a4 = *(const float4*)&As[kk][ty << 2];
            float4 b4 = *(const float4*)&Bs[kk][tx << 2];
            const float a[4] = { a4.x, a4.y, a4.z, a4.w };
            const float b[4] = { b4.x, b4.y, b4.z, b4.w };
#pragma unroll
            for (int i = 0; i < 4; ++i)
#pragma unroll
                for (int j = 0; j < 4; ++j)
                    acc[i][j] = fmaf(a[i], b[j], acc[i][j]);
        }
        __syncthreads();
    }

#pragma unroll
    for (int i = 0; i < 4; ++i) {
        const int m = m0 + (ty << 2) + i;
#pragma unroll
        for (int j = 0; j < 4; ++j) {
            const int n = n0 + (tx << 2) + j;
            if (n >= N) continue;
            float v = acc[i][j];
            if (SPLIT || EPI == EPI_NONE) {
                Cout[m * N + n] = v;
            } else if (EPI == EPI_SOFTPLUS) {
                v += bias[n];
                Cout[m * N + n] = fmaxf(v, 0.0f) + log1pf(__expf(-fabsf(v)));
            }
        }
    }
}

// ---------------------------------------------------------------------------
// split-K reduces
// ---------------------------------------------------------------------------
template<int EPI>
__global__ __launch_bounds__(256) void splitk_reduce(
    const float* __restrict__ part, float* __restrict__ C,
    int MN, int N, int S, const float* __restrict__ bias)
{
    const int i = blockIdx.x * 256 + threadIdx.x;
    if (i >= MN) return;
    float s = 0.0f;
    for (int j = 0; j < S; ++j) s += part[(size_t)j * MN + i];
    if (EPI == EPI_BIAS) s += bias[i % N];
    C[i] = s;
}

__global__ __launch_bounds__(256) void splitk_reduce_resid_bf16(
    const float* __restrict__ part, const float* __restrict__ resid,
    unsigned short* __restrict__ outb, int MN, int S)
{
    const int i = blockIdx.x * 256 + threadIdx.x;
    if (i >= MN) return;
    float s = 0.0f;
    for (int j = 0; j < S; ++j) s += part[(size_t)j * MN + i];
    outb[i] = f2bf(s + resid[i]);
}

// ---------------------------------------------------------------------------
// RMSNorm over rows of 1024 -> bf16 output
// ---------------------------------------------------------------------------
__global__ __launch_bounds__(256) void rmsnorm_k(
    const float* __restrict__ x, const float* __restrict__ w,
    unsigned short* __restrict__ o)
{
    const int row = blockIdx.x;
    const int t = threadIdx.x;
    const float* xr = x + row * DM;
    float4 xv = *(const float4*)&xr[t * 4];
    float ss = xv.x * xv.x + xv.y * xv.y + xv.z * xv.z + xv.w * xv.w;
#pragma unroll
    for (int off = 32; off > 0; off >>= 1) ss += __shfl_xor(ss, off);
    __shared__ float red[4];
    if ((t & 63) == 0) red[t >> 6] = ss;
    __syncthreads();
    const float tot = red[0] + red[1] + red[2] + red[3];
    const float scale = rsqrtf(tot * (1.0f / DM) + 1e-5f);
    float4 wv = *(const float4*)&w[t * 4];
    u16x4 ov;
    ov[0] = f2bf(xv.x * scale * wv.x); ov[1] = f2bf(xv.y * scale * wv.y);
    ov[2] = f2bf(xv.z * scale * wv.z); ov[3] = f2bf(xv.w * scale * wv.w);
    *(u16x4*)&o[row * DM + t * 4] = ov;
}

// ---------------------------------------------------------------------------
// causal depthwise conv (width 4) + bias + silu
// ---------------------------------------------------------------------------
__global__ __launch_bounds__(256) void conv_silu_k(
    const float* __restrict__ xz, const float* __restrict__ cw,
    const float* __restrict__ cb, float* __restrict__ u)
{
    const int idx = blockIdx.x * 256 + threadIdx.x;
    if (idx >= ML * DI) return;
    const int d  = idx & (DI - 1);
    const int bl = idx >> 11;
    const int l  = bl & (LL - 1);
    float s = cb[d];
#pragma unroll
    for (int w = 0; w < 4; ++w) {
        const int ls = l - 3 + w;
        if (ls >= 0) s = fmaf(xz[(bl - 3 + w) * (2 * DI) + d], cw[w * DI + d], s);
    }
    u[idx] = s * sigmoid_f(s);
}

// ---------------------------------------------------------------------------
// selective scan + D-skip + silu(z) gating -> bf16 y.  (r4 structure: 8-step
// chunks, batched loads, deferred level-major shuffle reduction)
// ---------------------------------------------------------------------------
__global__ __launch_bounds__(256) void scan_k(
    const float* __restrict__ dt, const float* __restrict__ u,
    const float* __restrict__ xz, const float* __restrict__ dbc,
    const float* __restrict__ A_log, const float* __restrict__ Dskip,
    unsigned short* __restrict__ y)
{
    const int t = blockIdx.x * 256 + threadIdx.x;
    const int n  = t & (DS - 1);
    const int ch = t >> 4;
    const int d  = ch & (DI - 1);
    const int b  = ch >> 11;
    const float a  = -__expf(A_log[d * DS + n]);
    const float Dv = Dskip[d];
    float h = 0.0f;
    const int rbase = b * LL;

    for (int l0 = 0; l0 < LL; l0 += 8) {
        float dtv[8], uv[8], Bv[8], Cv[8], zv[8];
#pragma unroll
        for (int s = 0; s < 8; ++s) {
            const int r = rbase + l0 + s;
            dtv[s] = dt[r * DI + d];
            uv[s]  = u[r * DI + d];
            Bv[s]  = dbc[r * 96 + DTR + n];
            Cv[s]  = dbc[r * 96 + DTR + DS + n];
            zv[s]  = xz[r * (2 * DI) + DI + d];
        }
        float p[8];
#pragma unroll
        for (int s = 0; s < 8; ++s) {
            const float dA = __expf(dtv[s] * a);
            h = fmaf(dA, h, dtv[s] * uv[s] * Bv[s]);
            p[s] = h * Cv[s];
        }
#pragma unroll
        for (int s = 0; s < 8; ++s) p[s] += __shfl_xor(p[s], 1);
#pragma unroll
        for (int s = 0; s < 8; ++s) p[s] += __shfl_xor(p[s], 2);
#pragma unroll
        for (int s = 0; s < 8; ++s) p[s] += __shfl_xor(p[s], 4);
#pragma unroll
        for (int s = 0; s < 8; ++s) p[s] += __shfl_xor(p[s], 8);
        if (n == 0) {
#pragma unroll
            for (int s = 0; s < 8; ++s) {
                const int r = rbase + l0 + s;
                const float yy = fmaf(Dv, uv[s], p[s]);
                y[r * DI + d] = f2bf(yy * zv[s] * sigmoid_f(zv[s]));
            }
        }
    }
}

// ---------------------------------------------------------------------------
extern "C" void kernel_launch(void* const* d_in, const int* in_sizes, int n_in,
                              void* d_out, int out_size, void* d_ws, size_t ws_size,
                              hipStream_t stream)
{
    const float* x        = (const float*)d_in[0];
    const float* enc_w    = (const float*)d_in[1];
    const float* enc_b    = (const float*)d_in[2];
    const float* dec_w    = (const float*)d_in[3];
    const float* dec_b    = (const float*)d_in[4];
    const float* norm_w   = (const float*)d_in[5];
    const float* in_proj  = (const float*)d_in[6];
    const float* conv_w   = (const float*)d_in[7];
    const float* conv_b   = (const float*)d_in[8];
    const float* x_proj   = (const float*)d_in[9];
    const float* dt_projw = (const float*)d_in[10];
    const float* dt_projb = (const float*)d_in[11];
    const float* A_log    = (const float*)d_in[12];
    const float* D_skip   = (const float*)d_in[13];
    const float* out_proj = (const float*)d_in[14];
    float* out = (float*)d_out;
    (void)in_sizes; (void)n_in; (void)out_size; (void)ws_size;

    // ---- workspace layout (bytes), peak ~134 MiB (r3 used 166: safe) ----
    char* wsb = (char*)d_ws;
    unsigned short* wbf = (unsigned short*)(wsb);              // [0,64Mi) enc_w bf16, later dec_w bf16
    float* part = (float*)(wsb + 67108864);                    // [64Mi,96Mi) split-K partials (16 slices)
    float* lat  = (float*)(wsb + 100663296);                   // 2 MiB
    float* dt   = (float*)(wsb + 102760448);                   // 4 MiB
    // Region S (32 MiB): xbf during encoder, then overlaid
    char* S0 = wsb + 106954752;
    unsigned short* xbf    = (unsigned short*)(S0);            // 32 MiB (encoder only)
    unsigned short* xnbf   = (unsigned short*)(S0);            // 1 MiB  (after encoder)
    unsigned short* ybf    = (unsigned short*)(S0 + 1048576);  // 2 MiB
    unsigned short* houtbf = (unsigned short*)(S0 + 3145728);  // 1 MiB
    float* xz  = (float*)(S0 + 4194304);                       // 8 MiB
    float* u   = (float*)(S0 + 12582912);                      // 4 MiB
    float* dbc = (float*)(S0 + 16777216);                      // 192 KiB

    // 1) convert x ({0,1} exact) and enc_w to bf16
    cvt_bf16_k<<<(FLAT * ML / 8) / 256, 256, 0, stream>>>(x, xbf, FLAT * ML / 8);
    cvt_bf16_k<<<(DM * FLAT / 8) / 256, 256, 0, stream>>>(enc_w, wbf, DM * FLAT / 8);

    // 2) encoder GEMM (split-K 16, 2-phase dbuf): lat = x @ enc_w^T + enc_b
    {
        dim3 g(ML / 128, DM / 128, 16);
        gemm_db<EPI_NONE, true><<<g, 256, 0, stream>>>(
            xbf, wbf, part, ML, DM, FLAT, FLAT, FLAT, FLAT / 16, nullptr);
        splitk_reduce<EPI_BIAS><<<(ML * DM) / 256, 256, 0, stream>>>(part, lat, ML * DM, DM, 16, enc_b);
    }
    // ---- xbf dead from here; region S reused ----

    // 3) rmsnorm -> bf16
    rmsnorm_k<<<ML, 256, 0, stream>>>(lat, norm_w, xnbf);

    // 4) in_proj (fused f32 B, single-buffer): xz = xn @ in_proj^T
    {
        dim3 g(ML / 128, (2 * DI) / 128);
        gemm_bf16<EPI_NONE, false, true><<<g, 256, 0, stream>>>(
            xnbf, in_proj, xz, ML, 2 * DI, DM, DM, DM, 0, nullptr);
    }

    // 5) conv + silu -> u (f32)
    conv_silu_k<<<(ML * DI) / 256, 256, 0, stream>>>(xz, conv_w, conv_b, u);

    // 6) x_proj (f32, split-K 16): dbc = u @ x_proj^T
    {
        dim3 g(ML / 64, 2, 16);
        gemm_nt<EPI_NONE, true><<<g, 256, 0, stream>>>(u, x_proj, part, ML, 96, DI, DI, DI,
                                                       DI / 16, nullptr);
        splitk_reduce<EPI_NONE><<<(ML * 96 + 255) / 256, 256, 0, stream>>>(part, dbc, ML * 96, 96, 16, nullptr);
    }

    // 7) dt = softplus(dbc[:, :64] @ dt_proj_w^T + dt_proj_b)
    {
        dim3 g(ML / 64, DI / 64);
        gemm_nt<EPI_SOFTPLUS, false><<<g, 256, 0, stream>>>(dbc, dt_projw, dt, ML, DI, DTR,
                                                            96, DTR, 0, dt_projb);
    }

    // 8) selective scan + gating -> ybf
    scan_k<<<(BB * DI * DS) / 256, 256, 0, stream>>>(dt, u, xz, dbc, A_log, D_skip, ybf);

    // 9) out_proj (split-K 8, fused f32 B) + residual(lat) -> houtbf
    {
        dim3 g(ML / 128, DM / 128, 8);
        gemm_bf16<EPI_NONE, true, true><<<g, 256, 0, stream>>>(
            ybf, out_proj, part, ML, DM, DI, DI, DI, DI / 8, nullptr);
        splitk_reduce_resid_bf16<<<(ML * DM) / 256, 256, 0, stream>>>(part, lat, houtbf, ML * DM, 8);
    }

    // 10) decoder (2-phase dbuf, bf16 dec_w): out = sigmoid(hout @ dec_w^T + dec_b)
    cvt_bf16_k<<<(FLAT * DM / 8) / 256, 256, 0, stream>>>(dec_w, wbf, FLAT * DM / 8);
    {
        dim3 g(ML / 128, FLAT / 128);
        gemm_db<EPI_DEC, false><<<g, 256, 0, stream>>>(
            houtbf, wbf, out, ML, FLAT, DM, DM, DM, 0, dec_b);
    }
}

// Round 10
// 624.211 us; speedup vs baseline: 1.1119x; 1.0148x over previous
//
#include <hip/hip_runtime.h>
#include <math.h>
#include <stdint.h>

// ---------------- problem constants ----------------
#define BB 2
#define LL 256
#define FLAT 32768
#define DM 1024            // D_MODEL
#define DI 2048            // D_INNER
#define DS 16              // D_STATE
#define DTR 64             // DT_RANK
#define ML (BB*LL)         // 512 rows everywhere

// epilogue selectors
#define EPI_NONE 0
#define EPI_BIAS 1
#define EPI_SOFTPLUS 2
#define EPI_DEC 4          // sigmoid(acc+bias) -> scatter, drop l==255 rows

typedef __attribute__((ext_vector_type(8))) short bf16x8;   // 8 bf16 (4 VGPRs)
typedef __attribute__((ext_vector_type(4))) float f32x4;
typedef __attribute__((ext_vector_type(8))) unsigned short u16x8;
typedef __attribute__((ext_vector_type(4))) unsigned short u16x4;

__device__ __forceinline__ float sigmoid_f(float x) { return 1.0f / (1.0f + __expf(-x)); }

// f32 -> bf16 round-to-nearest-even (inputs finite)
__device__ __forceinline__ unsigned short f2bf(float f) {
    unsigned u = __float_as_uint(f);
    u += 0x7fffu + ((u >> 16) & 1u);
    return (unsigned short)(u >> 16);
}

// packed f32x2 -> bf16x2 (RNE, hardware) — no builtin on gfx950, inline asm
__device__ __forceinline__ unsigned cvt_pk_bf16(float a, float b) {
    unsigned r;
    asm("v_cvt_pk_bf16_f32 %0, %1, %2" : "=v"(r) : "v"(a), "v"(b));
    return r;
}

__device__ __forceinline__ void gld_lds16(const void* g, void* l) {
    __builtin_amdgcn_global_load_lds(
        (const __attribute__((address_space(1))) unsigned int*)g,
        (__attribute__((address_space(3))) unsigned int*)l, 16, 0, 0);
}

// ---------------------------------------------------------------------------
// f32 -> bf16 bulk convert, 8 elems/thread (x only)
// ---------------------------------------------------------------------------
__global__ __launch_bounds__(256) void cvt_bf16_k(
    const float* __restrict__ in, unsigned short* __restrict__ out, int n8)
{
    const int i = blockIdx.x * 256 + threadIdx.x;
    if (i >= n8) return;
    const float4 a = ((const float4*)in)[2 * i];
    const float4 b = ((const float4*)in)[2 * i + 1];
    u16x8 r;
    r[0] = f2bf(a.x); r[1] = f2bf(a.y); r[2] = f2bf(a.z); r[3] = f2bf(a.w);
    r[4] = f2bf(b.x); r[5] = f2bf(b.y); r[6] = f2bf(b.z); r[7] = f2bf(b.w);
    ((u16x8*)out)[i] = r;
}

// ---------------------------------------------------------------------------
// 2-phase dbuf MFMA NT GEMM, A bf16 (global_load_lds direct), B *f32* with
// FUSED convert: B is loaded to REGISTERS (issued before the compute phase,
// T14 issue-early/write-late), converted via v_cvt_pk_bf16_f32 and
// ds_write_b128'd into the bf16 LDS buffer after compute. Kills the
// standalone enc_w/dec_w cvt passes (~192MB each) while keeping LDS at
// 2x32K (2 blocks/CU). Granule map & XOR swizzle identical to the pure-bf16
// path (cvt_pk packs k-order lo/hi), so the A/B fragment k-maps stay equal.
// 128x128 tile, BK=64, 256 thr (4 waves 2x2).
// ---------------------------------------------------------------------------
template<int EPI, bool SPLIT>
__global__ __launch_bounds__(256) void gemm_db2(
    const unsigned short* __restrict__ A, const float* __restrict__ Bf,
    float* __restrict__ C, int M, int N, int K, int lda, int ldb, int kChunk,
    const float* __restrict__ bias)
{
    __shared__ __align__(16) char lds[65536];   // buf p: A at p*32768, B at +16384

    const int t  = threadIdx.x;
    const int w  = t >> 6;
    const int l  = t & 63;
    const int m0 = blockIdx.x * 128;
    const int n0 = blockIdx.y * 128;
    const int wr = w >> 1, wc = w & 1;

    int kb = 0, ke = K;
    float* Cout = C;
    if (SPLIT) { kb = blockIdx.z * kChunk; ke = kb + kChunk;
                 Cout = C + (size_t)blockIdx.z * M * N; }

    const int srow0 = w * 32 + (l >> 3);
    const int ssub  = l & 7;

    f32x4 acc[4][4];
#pragma unroll
    for (int i = 0; i < 4; ++i)
#pragma unroll
        for (int j = 0; j < 4; ++j) acc[i][j] = (f32x4){0.f, 0.f, 0.f, 0.f};

    const int lr = l & 15, h = l >> 4;

    float4 breg[4][2];   // in-flight B f32 (32 VGPRs)

    // A: direct async stage into buffer p (linear dest, pre-swizzled source)
    auto STAGE_A = [&](int p, int kt) {
#pragma unroll
        for (int q = 0; q < 4; ++q) {
            const int row = srow0 + q * 8;
            gld_lds16(A + (size_t)(m0 + row) * lda + kt + ((ssub ^ (row & 7)) << 3),
                      lds + p * 32768 + w * 4096 + q * 1024);
        }
    };
    // B: issue f32 loads (8 float4) — placed BEFORE compute so HBM latency
    // hides under the MFMAs
    auto LOAD_B = [&](int kt) {
#pragma unroll
        for (int q = 0; q < 4; ++q) {
            const int row = srow0 + q * 8;
            const int G = ssub ^ (row & 7);          // global granule (swizzle)
            const float4* src = (const float4*)&Bf[(size_t)(n0 + row) * ldb + kt + G * 8];
            breg[q][0] = src[0];
            breg[q][1] = src[1];
        }
    };
    // B: convert + write into buffer p at swizzled slot (row, ssub)
    auto WRITE_B = [&](int p) {
#pragma unroll
        for (int q = 0; q < 4; ++q) {
            const int row = srow0 + q * 8;
            union { unsigned u[4]; bf16x8 v; } cv;
            cv.u[0] = cvt_pk_bf16(breg[q][0].x, breg[q][0].y);
            cv.u[1] = cvt_pk_bf16(breg[q][0].z, breg[q][0].w);
            cv.u[2] = cvt_pk_bf16(breg[q][1].x, breg[q][1].y);
            cv.u[3] = cvt_pk_bf16(breg[q][1].z, breg[q][1].w);
            *(bf16x8*)(lds + p * 32768 + 16384 + row * 128 + ssub * 16) = cv.v;
        }
    };

    // prologue: fill buffer 0
    STAGE_A(0, kb);
    LOAD_B(kb);
    WRITE_B(0);                    // compiler waits vmcnt for breg use
    __syncthreads();               // drains vm (gld_lds) + lgkm (ds_write)

    const int nt = (ke - kb) >> 6;
    int cur = 0;
    for (int tt = 0; tt < nt; ++tt) {
        if (tt + 1 < nt) {
            const int ktn = kb + ((tt + 1) << 6);
            STAGE_A(cur ^ 1, ktn);     // async into other buffer
            LOAD_B(ktn);               // f32 loads in flight during compute
        }
        const char* la = lds + cur * 32768;
        const char* lb = la + 16384;
#pragma unroll
        for (int ks = 0; ks < 2; ++ks) {
            bf16x8 af[4], bfr[4];
#pragma unroll
            for (int i = 0; i < 4; ++i) {
                const int r = wr * 64 + i * 16 + lr;
                const int sub = (ks * 4 + h) ^ (r & 7);
                af[i] = *(const bf16x8*)(la + r * 128 + sub * 16);
            }
#pragma unroll
            for (int j = 0; j < 4; ++j) {
                const int c = wc * 64 + j * 16 + lr;
                const int sub = (ks * 4 + h) ^ (c & 7);
                bfr[j] = *(const bf16x8*)(lb + c * 128 + sub * 16);
            }
#pragma unroll
            for (int i = 0; i < 4; ++i)
#pragma unroll
                for (int j = 0; j < 4; ++j)
                    acc[i][j] = __builtin_amdgcn_mfma_f32_16x16x32_bf16(
                        af[i], bfr[j], acc[i][j], 0, 0, 0);
        }
        if (tt + 1 < nt) WRITE_B(cur ^ 1);   // cvt+write after compute (T14)
        __syncthreads();                      // full drain: cheap, loads had
        cur ^= 1;                             // the whole compute to finish
    }

    // epilogue — C/D layout (m89-verified): col = lane&15, row = (lane>>4)*4 + reg
#pragma unroll
    for (int i = 0; i < 4; ++i)
#pragma unroll
        for (int j = 0; j < 4; ++j)
#pragma unroll
            for (int rg = 0; rg < 4; ++rg) {
                const int row = m0 + wr * 64 + i * 16 + h * 4 + rg;
                const int col = n0 + wc * 64 + j * 16 + lr;
                float v = acc[i][j][rg];
                if (SPLIT || EPI == EPI_NONE) {
                    Cout[(size_t)row * N + col] = v;
                } else if (EPI == EPI_DEC) {
                    v = sigmoid_f(v + bias[col]);
                    const int b = row >> 8, ll = row & 255;
                    if (ll < 255) Cout[(((size_t)(b * 255 + ll)) << 15) + col] = v;
                }
            }
}

// ---------------------------------------------------------------------------
// single-buffer MFMA NT GEMM with fused f32-B convert via LDS (r7 path, kept
// for the small cache-resident weights: in_proj 16MiB, out_proj 8MiB)
// ---------------------------------------------------------------------------
template<int EPI, bool SPLIT, bool BF32>
__global__ __launch_bounds__(256) void gemm_bf16(
    const unsigned short* __restrict__ A, const void* __restrict__ Bv,
    float* __restrict__ C, int M, int N, int K, int lda, int ldb, int kChunk,
    const float* __restrict__ bias)
{
    __shared__ __align__(16) char lds[BF32 ? 49152 : 32768];

    const float*          Bf = (const float*)Bv;
    const unsigned short* Bh = (const unsigned short*)Bv;

    const int t  = threadIdx.x;
    const int w  = t >> 6;
    const int l  = t & 63;
    const int m0 = blockIdx.x * 128;
    const int n0 = blockIdx.y * 128;
    const int wr = w >> 1, wc = w & 1;

    int kb = 0, ke = K;
    float* Cout = C;
    if (SPLIT) { kb = blockIdx.z * kChunk; ke = kb + kChunk;
                 Cout = C + (size_t)blockIdx.z * M * N; }

    const int srow0 = w * 32 + (l >> 3);
    const int ssub  = l & 7;
    const int brow0 = w * 32 + (l >> 4);
    const int bgl   = l & 15;

    f32x4 acc[4][4];
#pragma unroll
    for (int i = 0; i < 4; ++i)
#pragma unroll
        for (int j = 0; j < 4; ++j) acc[i][j] = (f32x4){0.f, 0.f, 0.f, 0.f};

    const int lr = l & 15, h = l >> 4;

    for (int kt = kb; kt < ke; kt += 64) {
#pragma unroll
        for (int q = 0; q < 4; ++q) {
            const int row = srow0 + q * 8;
            gld_lds16(A + (size_t)(m0 + row) * lda + kt + ((ssub ^ (row & 7)) << 3),
                      lds + w * 4096 + q * 1024);
        }
        if (BF32) {
#pragma unroll
            for (int q = 0; q < 8; ++q) {
                const int row = brow0 + q * 4;
                gld_lds16(Bf + (size_t)(n0 + row) * ldb + kt + ((bgl ^ (row & 15)) << 2),
                          lds + 16384 + w * 8192 + q * 1024);
            }
        } else {
#pragma unroll
            for (int q = 0; q < 4; ++q) {
                const int row = srow0 + q * 8;
                gld_lds16(Bh + (size_t)(n0 + row) * ldb + kt + ((ssub ^ (row & 7)) << 3),
                          lds + 16384 + w * 4096 + q * 1024);
            }
        }
        __syncthreads();

#pragma unroll
        for (int ks = 0; ks < 2; ++ks) {
            bf16x8 af[4], bfr[4];
#pragma unroll
            for (int i = 0; i < 4; ++i) {
                const int r = wr * 64 + i * 16 + lr;
                const int sub = (ks * 4 + h) ^ (r & 7);
                af[i] = *(const bf16x8*)(lds + r * 128 + sub * 16);
            }
#pragma unroll
            for (int j = 0; j < 4; ++j) {
                const int c = wc * 64 + j * 16 + lr;
                if (BF32) {
                    const int g0 = (2 * (ks * 4 + h))     ^ (c & 15);
                    const int g1 = (2 * (ks * 4 + h) + 1) ^ (c & 15);
                    const f32x4 v0 = *(const f32x4*)(lds + 16384 + c * 256 + g0 * 16);
                    const f32x4 v1 = *(const f32x4*)(lds + 16384 + c * 256 + g1 * 16);
                    union { unsigned u[4]; bf16x8 v; } cv;
                    cv.u[0] = cvt_pk_bf16(v0[0], v0[1]);
                    cv.u[1] = cvt_pk_bf16(v0[2], v0[3]);
                    cv.u[2] = cvt_pk_bf16(v1[0], v1[1]);
                    cv.u[3] = cvt_pk_bf16(v1[2], v1[3]);
                    bfr[j] = cv.v;
                } else {
                    const int sub = (ks * 4 + h) ^ (c & 7);
                    bfr[j] = *(const bf16x8*)(lds + 16384 + c * 128 + sub * 16);
                }
            }
#pragma unroll
            for (int i = 0; i < 4; ++i)
#pragma unroll
                for (int j = 0; j < 4; ++j)
                    acc[i][j] = __builtin_amdgcn_mfma_f32_16x16x32_bf16(
                        af[i], bfr[j], acc[i][j], 0, 0, 0);
        }
        __syncthreads();
    }

#pragma unroll
    for (int i = 0; i < 4; ++i)
#pragma unroll
        for (int j = 0; j < 4; ++j)
#pragma unroll
            for (int rg = 0; rg < 4; ++rg) {
                const int row = m0 + wr * 64 + i * 16 + h * 4 + rg;
                const int col = n0 + wc * 64 + j * 16 + lr;
                float v = acc[i][j][rg];
                if (SPLIT || EPI == EPI_NONE) {
                    Cout[(size_t)row * N + col] = v;
                } else if (EPI == EPI_DEC) {
                    v = sigmoid_f(v + bias[col]);
                    const int b = row >> 8, ll = row & 255;
                    if (ll < 255) Cout[(((size_t)(b * 255 + ll)) << 15) + col] = v;
                }
            }
}

// ---------------------------------------------------------------------------
// f32 NT GEMM (small ops only): 64x64 tile, BK=32
// ---------------------------------------------------------------------------
template<int EPI, bool SPLIT>
__global__ __launch_bounds__(256) void gemm_nt(
    const float* __restrict__ A, const float* __restrict__ B,
    float* __restrict__ C, int M, int N, int K, int lda, int ldb,
    int kChunk, const float* __restrict__ bias)
{
    __shared__ float As[32][64];
    __shared__ float Bs[32][64];

    const int m0 = blockIdx.x * 64;
    const int n0 = blockIdx.y * 64;
    const int t  = threadIdx.x;

    int kb = 0, ke = K;
    float* Cout = C;
    if (SPLIT) { kb = blockIdx.z * kChunk; ke = kb + kChunk; Cout = C + (size_t)blockIdx.z * M * N; }

    const int lrow = t >> 3;
    const int lcol = (t & 7) << 2;

    float acc[4][4];
#pragma unroll
    for (int i = 0; i < 4; ++i)
#pragma unroll
        for (int j = 0; j < 4; ++j) acc[i][j] = 0.0f;

    const int tx = t & 15, ty = t >> 4;

    for (int k = kb; k < ke; k += 32) {
#pragma unroll
        for (int i = 0; i < 2; ++i) {
            const int row = lrow + i * 32;
            float4 av = *(const float4*)&A[(m0 + row) * lda + k + lcol];
            As[lcol + 0][row] = av.x; As[lcol + 1][row] = av.y;
            As[lcol + 2][row] = av.z; As[lcol + 3][row] = av.w;
            const int nn = n0 + row;
            float4 bv = make_float4(0.f, 0.f, 0.f, 0.f);
            if (nn < N) bv = *(const float4*)&B[nn * ldb + k + lcol];
            Bs[lcol + 0][row] = bv.x; Bs[lcol + 1][row] = bv.y;
            Bs[lcol + 2][row] = bv.z; Bs[lcol + 3][row] = bv.w;
        }
        __syncthreads();
#pragma unroll
        for (int kk = 0; kk < 32; ++kk) {
            float4 a4 = *(const float4*)&As[kk][ty << 2];
            float4 b4 = *(const float4*)&Bs[kk][tx << 2];
            const float a[4] = { a4.x, a4.y, a4.z, a4.w };
            const float b[4] = { b4.x, b4.y, b4.z, b4.w };
#pragma unroll
            for (int i = 0; i < 4; ++i)
#pragma unroll
                for (int j = 0; j < 4; ++j)
                    acc[i][j] = fmaf(a[i], b[j], acc[i][j]);
        }
        __syncthreads();
    }

#pragma unroll
    for (int i = 0; i < 4; ++i) {
        const int m = m0 + (ty << 2) + i;
#pragma unroll
        for (int j = 0; j < 4; ++j) {
            const int n = n0 + (tx << 2) + j;
            if (n >= N) continue;
            float v = acc[i][j];
            if (SPLIT || EPI == EPI_NONE) {
                Cout[m * N + n] = v;
            } else if (EPI == EPI_SOFTPLUS) {
                v += bias[n];
                Cout[m * N + n] = fmaxf(v, 0.0f) + log1pf(__expf(-fabsf(v)));
            }
        }
    }
}

// ---------------------------------------------------------------------------
// split-K reduces (x_proj path) + fused encoder reduce+bias+rmsnorm
// ---------------------------------------------------------------------------
template<int EPI>
__global__ __launch_bounds__(256) void splitk_reduce(
    const float* __restrict__ part, float* __restrict__ C,
    int MN, int N, int S, const float* __restrict__ bias)
{
    const int i = blockIdx.x * 256 + threadIdx.x;
    if (i >= MN) return;
    float s = 0.0f;
    for (int j = 0; j < S; ++j) s += part[(size_t)j * MN + i];
    if (EPI == EPI_BIAS) s += bias[i % N];
    C[i] = s;
}

__global__ __launch_bounds__(256) void splitk_reduce_resid_bf16(
    const float* __restrict__ part, const float* __restrict__ resid,
    unsigned short* __restrict__ outb, int MN, int S)
{
    const int i = blockIdx.x * 256 + threadIdx.x;
    if (i >= MN) return;
    float s = 0.0f;
    for (int j = 0; j < S; ++j) s += part[(size_t)j * MN + i];
    outb[i] = f2bf(s + resid[i]);
}

// fused: encoder split-K reduce (+bias) -> lat, then rmsnorm(lat) -> bf16 xn.
// one block per row (512 blocks); thread t owns cols 4t..4t+3.
__global__ __launch_bounds__(256) void reduce_rms_k(
    const float* __restrict__ part, const float* __restrict__ bias,
    const float* __restrict__ w, float* __restrict__ lat,
    unsigned short* __restrict__ xn, int S)
{
    const int row = blockIdx.x;
    const int t = threadIdx.x;
    const float* p = part + (size_t)row * DM + t * 4;
    float4 s = make_float4(0.f, 0.f, 0.f, 0.f);
    for (int j = 0; j < S; ++j) {
        const float4 v = *(const float4*)(p + (size_t)j * (ML * DM));
        s.x += v.x; s.y += v.y; s.z += v.z; s.w += v.w;
    }
    const float4 bv = *(const float4*)&bias[t * 4];
    s.x += bv.x; s.y += bv.y; s.z += bv.z; s.w += bv.w;
    *(float4*)&lat[(size_t)row * DM + t * 4] = s;

    float ss = s.x * s.x + s.y * s.y + s.z * s.z + s.w * s.w;
#pragma unroll
    for (int off = 32; off > 0; off >>= 1) ss += __shfl_xor(ss, off);
    __shared__ float red[4];
    if ((t & 63) == 0) red[t >> 6] = ss;
    __syncthreads();
    const float tot = red[0] + red[1] + red[2] + red[3];
    const float scale = rsqrtf(tot * (1.0f / DM) + 1e-5f);
    const float4 wv = *(const float4*)&w[t * 4];
    u16x4 ov;
    ov[0] = f2bf(s.x * scale * wv.x); ov[1] = f2bf(s.y * scale * wv.y);
    ov[2] = f2bf(s.z * scale * wv.z); ov[3] = f2bf(s.w * scale * wv.w);
    *(u16x4*)&xn[(size_t)row * DM + t * 4] = ov;
}

// ---------------------------------------------------------------------------
// causal depthwise conv (width 4) + bias + silu
// ---------------------------------------------------------------------------
__global__ __launch_bounds__(256) void conv_silu_k(
    const float* __restrict__ xz, const float* __restrict__ cw,
    const float* __restrict__ cb, float* __restrict__ u)
{
    const int idx = blockIdx.x * 256 + threadIdx.x;
    if (idx >= ML * DI) return;
    const int d  = idx & (DI - 1);
    const int bl = idx >> 11;
    const int l  = bl & (LL - 1);
    float s = cb[d];
#pragma unroll
    for (int w = 0; w < 4; ++w) {
        const int ls = l - 3 + w;
        if (ls >= 0) s = fmaf(xz[(bl - 3 + w) * (2 * DI) + d], cw[w * DI + d], s);
    }
    u[idx] = s * sigmoid_f(s);
}

// ---------------------------------------------------------------------------
// selective scan + D-skip + silu(z) gating -> bf16 y.  (r4 structure: 8-step
// chunks, batched loads, deferred level-major shuffle reduction)
// ---------------------------------------------------------------------------
__global__ __launch_bounds__(256) void scan_k(
    const float* __restrict__ dt, const float* __restrict__ u,
    const float* __restrict__ xz, const float* __restrict__ dbc,
    const float* __restrict__ A_log, const float* __restrict__ Dskip,
    unsigned short* __restrict__ y)
{
    const int t = blockIdx.x * 256 + threadIdx.x;
    const int n  = t & (DS - 1);
    const int ch = t >> 4;
    const int d  = ch & (DI - 1);
    const int b  = ch >> 11;
    const float a  = -__expf(A_log[d * DS + n]);
    const float Dv = Dskip[d];
    float h = 0.0f;
    const int rbase = b * LL;

    for (int l0 = 0; l0 < LL; l0 += 8) {
        float dtv[8], uv[8], Bv[8], Cv[8], zv[8];
#pragma unroll
        for (int s = 0; s < 8; ++s) {
            const int r = rbase + l0 + s;
            dtv[s] = dt[r * DI + d];
            uv[s]  = u[r * DI + d];
            Bv[s]  = dbc[r * 96 + DTR + n];
            Cv[s]  = dbc[r * 96 + DTR + DS + n];
            zv[s]  = xz[r * (2 * DI) + DI + d];
        }
        float p[8];
#pragma unroll
        for (int s = 0; s < 8; ++s) {
            const float dA = __expf(dtv[s] * a);
            h = fmaf(dA, h, dtv[s] * uv[s] * Bv[s]);
            p[s] = h * Cv[s];
        }
#pragma unroll
        for (int s = 0; s < 8; ++s) p[s] += __shfl_xor(p[s], 1);
#pragma unroll
        for (int s = 0; s < 8; ++s) p[s] += __shfl_xor(p[s], 2);
#pragma unroll
        for (int s = 0; s < 8; ++s) p[s] += __shfl_xor(p[s], 4);
#pragma unroll
        for (int s = 0; s < 8; ++s) p[s] += __shfl_xor(p[s], 8);
        if (n == 0) {
#pragma unroll
            for (int s = 0; s < 8; ++s) {
                const int r = rbase + l0 + s;
                const float yy = fmaf(Dv, uv[s], p[s]);
                y[r * DI + d] = f2bf(yy * zv[s] * sigmoid_f(zv[s]));
            }
        }
    }
}

// ---------------------------------------------------------------------------
extern "C" void kernel_launch(void* const* d_in, const int* in_sizes, int n_in,
                              void* d_out, int out_size, void* d_ws, size_t ws_size,
                              hipStream_t stream)
{
    const float* x        = (const float*)d_in[0];
    const float* enc_w    = (const float*)d_in[1];
    const float* enc_b    = (const float*)d_in[2];
    const float* dec_w    = (const float*)d_in[3];
    const float* dec_b    = (const float*)d_in[4];
    const float* norm_w   = (const float*)d_in[5];
    const float* in_proj  = (const float*)d_in[6];
    const float* conv_w   = (const float*)d_in[7];
    const float* conv_b   = (const float*)d_in[8];
    const float* x_proj   = (const float*)d_in[9];
    const float* dt_projw = (const float*)d_in[10];
    const float* dt_projb = (const float*)d_in[11];
    const float* A_log    = (const float*)d_in[12];
    const float* D_skip   = (const float*)d_in[13];
    const float* out_proj = (const float*)d_in[14];
    float* out = (float*)d_out;
    (void)in_sizes; (void)n_in; (void)out_size; (void)ws_size;

    // ---- workspace layout (bytes), peak ~72 MiB (ws = 512 MiB per r9 fill) ----
    char* wsb = (char*)d_ws;
    float* part = (float*)(wsb);                               // [0,32Mi) split-K partials (16 slices)
    float* lat  = (float*)(wsb + 33554432);                    // 2 MiB
    float* dt   = (float*)(wsb + 35651584);                    // 4 MiB
    char* S0 = wsb + 41943040;                                 // region S
    unsigned short* xbf    = (unsigned short*)(S0);            // 32 MiB (encoder only)
    unsigned short* xnbf   = (unsigned short*)(S0);            // 1 MiB  (after encoder)
    unsigned short* ybf    = (unsigned short*)(S0 + 1048576);  // 2 MiB
    unsigned short* houtbf = (unsigned short*)(S0 + 3145728);  // 1 MiB
    float* xz  = (float*)(S0 + 4194304);                       // 8 MiB
    float* u   = (float*)(S0 + 12582912);                      // 4 MiB
    float* dbc = (float*)(S0 + 16777216);                      // 192 KiB

    // 1) convert x ({0,1} exact) to bf16 — the only standalone cvt left
    cvt_bf16_k<<<(FLAT * ML / 8) / 256, 256, 0, stream>>>(x, xbf, FLAT * ML / 8);

    // 2) encoder GEMM (split-K 16, 2-ph dbuf, fused f32->bf16 B): x @ enc_w^T
    {
        dim3 g(ML / 128, DM / 128, 16);
        gemm_db2<EPI_NONE, true><<<g, 256, 0, stream>>>(
            xbf, enc_w, part, ML, DM, FLAT, FLAT, FLAT, FLAT / 16, nullptr);
    }
    // 3) fused reduce(+enc_b) -> lat, rmsnorm -> xnbf   (was 2 dispatches)
    reduce_rms_k<<<ML, 256, 0, stream>>>(part, enc_b, norm_w, lat, xnbf, 16);
    // ---- xbf dead from here; region S reused ----

    // 4) in_proj (fused f32 B, single-buffer): xz = xn @ in_proj^T
    {
        dim3 g(ML / 128, (2 * DI) / 128);
        gemm_bf16<EPI_NONE, false, true><<<g, 256, 0, stream>>>(
            xnbf, in_proj, xz, ML, 2 * DI, DM, DM, DM, 0, nullptr);
    }

    // 5) conv + silu -> u (f32)
    conv_silu_k<<<(ML * DI) / 256, 256, 0, stream>>>(xz, conv_w, conv_b, u);

    // 6) x_proj (f32, split-K 16): dbc = u @ x_proj^T
    {
        dim3 g(ML / 64, 2, 16);
        gemm_nt<EPI_NONE, true><<<g, 256, 0, stream>>>(u, x_proj, part, ML, 96, DI, DI, DI,
                                                       DI / 16, nullptr);
        splitk_reduce<EPI_NONE><<<(ML * 96 + 255) / 256, 256, 0, stream>>>(part, dbc, ML * 96, 96, 16, nullptr);
    }

    // 7) dt = softplus(dbc[:, :64] @ dt_proj_w^T + dt_proj_b)
    {
        dim3 g(ML / 64, DI / 64);
        gemm_nt<EPI_SOFTPLUS, false><<<g, 256, 0, stream>>>(dbc, dt_projw, dt, ML, DI, DTR,
                                                            96, DTR, 0, dt_projb);
    }

    // 8) selective scan + gating -> ybf
    scan_k<<<(BB * DI * DS) / 256, 256, 0, stream>>>(dt, u, xz, dbc, A_log, D_skip, ybf);

    // 9) out_proj (split-K 8, fused f32 B) + residual(lat) -> houtbf
    {
        dim3 g(ML / 128, DM / 128, 8);
        gemm_bf16<EPI_NONE, true, true><<<g, 256, 0, stream>>>(
            ybf, out_proj, part, ML, DM, DI, DI, DI, DI / 8, nullptr);
        splitk_reduce_resid_bf16<<<(ML * DM) / 256, 256, 0, stream>>>(part, lat, houtbf, ML * DM, 8);
    }

    // 10) decoder (2-ph dbuf, fused f32->bf16 B): sigmoid(hout @ dec_w^T + dec_b)
    {
        dim3 g(ML / 128, FLAT / 128);
        gemm_db2<EPI_DEC, false><<<g, 256, 0, stream>>>(
            houtbf, dec_w, out, ML, FLAT, DM, DM, DM, 0, dec_b);
    }
}